// Round 7
// baseline (297.429 us; speedup 1.0000x reference)
//
#include <hip/hip_runtime.h>
#include <hip/hip_bf16.h>
#include <math.h>

// Problem constants
constexpr int Bn     = 2;
constexpr int Lseq   = 1024;
constexpr int DM     = 512;    // d_model
constexpr int DI     = 1024;   // d_inner
constexpr int DS     = 64;     // d_state
constexpr int RNK    = 32;     // dt_rank
constexpr int NROWS  = Bn * Lseq;  // 2048
constexpr int XDBW   = RNK + 2 * DS; // 160
constexpr int CH     = 64;     // scan chunk length
constexpr int NC     = Lseq / CH;  // 16 chunks

typedef __attribute__((ext_vector_type(4))) float floatx4;
typedef __attribute__((ext_vector_type(8))) short shortx8;

__device__ __forceinline__ float silu_f(float v) {
    return v / (1.f + __expf(-v));
}

__device__ __forceinline__ float rdl(float v, int l) {
    return __int_as_float(__builtin_amdgcn_readlane(__float_as_int(v), l));
}

// ---------------- LayerNorm -> bf16 ----------------
__global__ void ln_kernel(const float* __restrict__ x, const float* __restrict__ g,
                          const float* __restrict__ be, __hip_bfloat16* __restrict__ xn) {
    int row = blockIdx.x;
    int tid = threadIdx.x;
    const float* xr = x + (size_t)row * DM;
    float v0 = xr[tid], v1 = xr[tid + 256];
    float s = v0 + v1, sq = v0 * v0 + v1 * v1;
    #pragma unroll
    for (int o = 1; o < 64; o <<= 1) {
        s  += __shfl_xor(s, o);
        sq += __shfl_xor(sq, o);
    }
    __shared__ float red[8];
    int w = tid >> 6;
    if ((tid & 63) == 0) { red[w] = s; red[4 + w] = sq; }
    __syncthreads();
    float ts = red[0] + red[1] + red[2] + red[3];
    float tq = red[4] + red[5] + red[6] + red[7];
    float mu  = ts * (1.f / DM);
    float var = tq * (1.f / DM) - mu * mu;
    float inv = rsqrtf(var + 1e-5f);
    __hip_bfloat16* o0 = xn + (size_t)row * DM;
    o0[tid]       = __float2bfloat16((v0 - mu) * inv * g[tid]       + be[tid]);
    o0[tid + 256] = __float2bfloat16((v1 - mu) * inv * g[tid + 256] + be[tid + 256]);
}

// ---------------- Transpose + cast: in fp32 [R][Cc] -> out bf16 [Cc][R], bounds-guarded ----
__global__ void transpose_cast(const float* __restrict__ in, __hip_bfloat16* __restrict__ out,
                               int R, int Cc) {
    __shared__ float tile[64][65];
    const float* inb = in + (size_t)blockIdx.z * R * Cc;
    __hip_bfloat16* outb = out + (size_t)blockIdx.z * R * Cc;
    int r0 = blockIdx.y * 64, c0 = blockIdx.x * 64;
    int tid = threadIdx.x;
    #pragma unroll
    for (int i = tid; i < 4096; i += 256) {
        int r = i >> 6, c = i & 63;
        tile[r][c] = (r0 + r < R && c0 + c < Cc) ? inb[(size_t)(r0 + r) * Cc + c0 + c] : 0.f;
    }
    __syncthreads();
    #pragma unroll
    for (int i = tid; i < 4096; i += 256) {
        int c = i >> 6, r = i & 63;
        if (r0 + r < R && c0 + c < Cc)
            outb[(size_t)(c0 + c) * R + r0 + r] = __float2bfloat16(tile[r][c]);
    }
}

// ---------------- bf16 MFMA GEMM: C(MxN) = A(MxK) * Bt(NxK)^T  [+ Res] ----------------
template<bool RES>
__global__ __launch_bounds__(256) void gemm_bf16(const __hip_bfloat16* __restrict__ A,
                                                 const __hip_bfloat16* __restrict__ Bt,
                                                 const float* __restrict__ Res,
                                                 float* __restrict__ C,
                                                 int M, int N, int K) {
    __shared__ __hip_bfloat16 As[128 * 32];
    __shared__ __hip_bfloat16 Bs[128 * 32];
    const int tid  = threadIdx.x;
    const int wave = tid >> 6, lane = tid & 63;
    const int m0 = blockIdx.y * 128, n0 = blockIdx.x * 128;
    const int wm = (wave >> 1) * 64, wn = (wave & 1) * 64;

    floatx4 acc[4][4] = {};

    const int arow16 = lane & 15;
    const int kgrp   = lane >> 4;

    for (int k0 = 0; k0 < K; k0 += 32) {
        #pragma unroll
        for (int r = 0; r < 2; ++r) {
            int i   = wave * 64 + r * 256 + lane;   // 0..511
            int row = i >> 2, seg = i & 3;
            int brow = n0 + row; if (brow >= N) brow = N - 1;
            const __hip_bfloat16* gA = A  + (size_t)(m0 + row) * K + k0 + seg * 8;
            const __hip_bfloat16* gB = Bt + (size_t)brow * K + k0 + seg * 8;
            __hip_bfloat16* lA = As + (size_t)(wave * 64 + r * 256) * 8;
            __hip_bfloat16* lB = Bs + (size_t)(wave * 64 + r * 256) * 8;
            __builtin_amdgcn_global_load_lds(
                (const __attribute__((address_space(1))) void*)gA,
                (__attribute__((address_space(3))) void*)lA, 16, 0, 0);
            __builtin_amdgcn_global_load_lds(
                (const __attribute__((address_space(1))) void*)gB,
                (__attribute__((address_space(3))) void*)lB, 16, 0, 0);
        }
        __syncthreads();

        const shortx8* Asv = (const shortx8*)As;
        const shortx8* Bsv = (const shortx8*)Bs;
        shortx8 a[4], b[4];
        #pragma unroll
        for (int i = 0; i < 4; ++i)
            a[i] = Asv[(wm + i * 16 + arow16) * 4 + kgrp];
        #pragma unroll
        for (int j = 0; j < 4; ++j)
            b[j] = Bsv[(wn + j * 16 + arow16) * 4 + kgrp];
        #pragma unroll
        for (int i = 0; i < 4; ++i)
            #pragma unroll
            for (int j = 0; j < 4; ++j)
                acc[i][j] = __builtin_amdgcn_mfma_f32_16x16x32_bf16(a[i], b[j], acc[i][j], 0, 0, 0);
        __syncthreads();
    }

    const int drow = (lane >> 4) * 4;
    const int dcol = lane & 15;
    #pragma unroll
    for (int i = 0; i < 4; ++i)
        #pragma unroll
        for (int j = 0; j < 4; ++j) {
            int rowb = m0 + wm + i * 16 + drow;
            int col  = n0 + wn + j * 16 + dcol;
            if (col < N) {
                #pragma unroll
                for (int r = 0; r < 4; ++r) {
                    size_t idx = (size_t)(rowb + r) * N + col;
                    float v = acc[i][j][r];
                    if (RES) v += Res[idx];
                    C[idx] = v;
                }
            }
        }
}

// ---------------- Causal depthwise conv (taps=4) + bias + SiLU, dual fp32/bf16 out -------
__global__ void conv_silu(const float* __restrict__ xz, const float* __restrict__ cw,
                          const float* __restrict__ cb, float* __restrict__ xcv,
                          __hip_bfloat16* __restrict__ xcv_bf) {
    int idx = blockIdx.x * 256 + threadIdx.x;   // (b*L + t)*DI + d
    int d = idx & (DI - 1);
    int bt = idx / DI;
    int t = bt & (Lseq - 1);
    int b = bt / Lseq;
    float acc = cb[d];
    #pragma unroll
    for (int k = 0; k < 4; ++k) {
        int tt = t - 3 + k;
        float xv = (tt >= 0) ? xz[((size_t)(b * Lseq + tt)) * (2 * DI) + d] : 0.f;
        acc += xv * cw[d * 4 + k];
    }
    float v = silu_f(acc);
    xcv[idx] = v;
    xcv_bf[idx] = __float2bfloat16(v);
}

// ---------------- delta = softplus(dt @ W_dt + b_dt) ----------------
__global__ void delta_kernel(const float* __restrict__ xdb, const float* __restrict__ Wdt,
                             const float* __restrict__ bdt, float* __restrict__ delta) {
    int row = blockIdx.y;
    int d = blockIdx.x * 256 + threadIdx.x;
    __shared__ float dtv[RNK];
    if (threadIdx.x < RNK) dtv[threadIdx.x] = xdb[(size_t)row * XDBW + threadIdx.x];
    __syncthreads();
    float acc = bdt[d];
    #pragma unroll
    for (int r = 0; r < RNK; ++r) acc += dtv[r] * Wdt[(size_t)r * DI + d];
    float sp = (acc > 20.f) ? acc : log1pf(__expf(acc));
    delta[(size_t)row * DI + d] = sp;
}

// ============ Chunked scan, phase 1: local scan per chunk (h0=0) + chunk delta-sum =======
// block: 512 thr = 8 waves; wave w handles d = dg*8+w, lane = state s.
// delta / delta*x live in registers (lane=t) and are broadcast via v_readlane.
__global__ __launch_bounds__(512) void scan_chunk1(
        const float* __restrict__ delta, const float* __restrict__ xcv,
        const float* __restrict__ xdb, const float* __restrict__ A_log,
        float* __restrict__ hend, float* __restrict__ dsum) {
    __shared__ float Bsh[64][68];
    __shared__ float dsh[8][64];
    __shared__ float xsh[8][64];

    int blk = blockIdx.x;
    int dg  = blk & (DI / 8 - 1);   // 0..127
    int bc  = blk >> 7;             // b*NC + c
    int c = bc & (NC - 1), b = bc >> 4;
    int tid = threadIdx.x, w = tid >> 6, lane = tid & 63;
    int d = dg * 8 + w;
    int r0 = b * Lseq + c * CH;

    // stage B (cols 32..95 of xdb), float4
    #pragma unroll
    for (int k = 0; k < 2; ++k) {
        int idx = tid + k * 512;          // 0..1023
        int row = idx >> 4, j4 = idx & 15;
        float4 v = *(const float4*)&xdb[(size_t)(r0 + row) * XDBW + RNK + j4 * 4];
        *(float4*)&Bsh[row][j4 * 4] = v;
    }
    {
        int t = tid >> 3, ww = tid & 7;
        dsh[ww][t] = delta[(size_t)(r0 + t) * DI + dg * 8 + ww];
        xsh[ww][t] = xcv[(size_t)(r0 + t) * DI + dg * 8 + ww];
    }
    __syncthreads();

    float a = -__expf(A_log[d * DS + lane]);
    float vd  = dsh[w][lane];           // delta for t=lane
    float vpx = vd * xsh[w][lane];      // delta*x for t=lane
    float h = 0.f;
    #pragma unroll 16
    for (int t = 0; t < CH; ++t) {
        float dt_ = rdl(vd, t);
        float px  = rdl(vpx, t);
        h = h * __expf(dt_ * a) + px * Bsh[t][lane];
    }
    float S = vd;
    #pragma unroll
    for (int o = 1; o < 64; o <<= 1) S += __shfl_xor(S, o);
    size_t base = ((size_t)bc * DI + d) * 64;
    hend[base + lane] = h;
    if (lane == 0) dsum[(size_t)bc * DI + d] = S;
}

// ============ Chunked scan, phase 2: stitch across chunks ============
__global__ __launch_bounds__(256) void scan_stitch(
        const float* __restrict__ hend, const float* __restrict__ dsum,
        const float* __restrict__ A_log, float* __restrict__ hstart) {
    int idx = blockIdx.x * 4 + (threadIdx.x >> 6);   // b*DI + d
    int lane = threadIdx.x & 63;
    int b = idx >> 10, d = idx & (DI - 1);
    float a = -__expf(A_log[d * DS + lane]);
    float h = 0.f;
    #pragma unroll
    for (int c = 0; c < NC; ++c) {
        size_t base = ((size_t)(b * NC + c) * DI + d) * 64;
        hstart[base + lane] = h;
        float he = hend[base + lane];
        float S  = dsum[(size_t)(b * NC + c) * DI + d];
        h = he + __expf(a * S) * h;
    }
}

// ============ Chunked scan, phase 3: recompute with correct h_start, emit y ============
// BC interleaved [t][2s,2s+1] -> one ds_read_b64 per t (contiguous, conflict-free).
// P row stride 69: reduce-read bank = (5*tr + 16*q + j) mod 32 -> max 2 lanes/bank (free).
__global__ __launch_bounds__(512) void scan_chunk2(
        const float* __restrict__ delta, const float* __restrict__ xcv,
        const float* __restrict__ xdb, const float* __restrict__ xz,
        const float* __restrict__ A_log, const float* __restrict__ Dp,
        const float* __restrict__ hstart, float* __restrict__ yT) {
    __shared__ float BCsh[64][130];   // [t][2s+{0,1}] = (B[t][s], C[t][s])
    __shared__ float dsh[8][64];
    __shared__ float xsh[8][64];
    __shared__ float zsh[8][64];
    __shared__ float P[8][16 * 69];

    int blk = blockIdx.x;
    int dg  = blk & (DI / 8 - 1);
    int bc  = blk >> 7;
    int c = bc & (NC - 1), b = bc >> 4;
    int tid = threadIdx.x, w = tid >> 6, lane = tid & 63;
    int d = dg * 8 + w;
    int r0 = b * Lseq + c * CH;

    // stage B and C interleaved: per i, one float4 of B and one of C for (t, s-range)
    #pragma unroll
    for (int k = 0; k < 2; ++k) {
        int i = tid + k * 512;            // 0..1023
        int t = i >> 4, sg = i & 15;
        const float* rowp = &xdb[(size_t)(r0 + t) * XDBW + RNK];
        float4 bv = *(const float4*)&rowp[sg * 4];
        float4 cv = *(const float4*)&rowp[DS + sg * 4];
        #pragma unroll
        for (int j = 0; j < 4; ++j) {
            int s = sg * 4 + j;
            *(float2*)&BCsh[t][2 * s] = make_float2((&bv.x)[j], (&cv.x)[j]);
        }
    }
    {
        int t = tid >> 3, ww = tid & 7;
        dsh[ww][t] = delta[(size_t)(r0 + t) * DI + dg * 8 + ww];
        xsh[ww][t] = xcv[(size_t)(r0 + t) * DI + dg * 8 + ww];
        zsh[ww][t] = xz[(size_t)(r0 + t) * (2 * DI) + DI + dg * 8 + ww];
    }
    __syncthreads();

    float a  = -__expf(A_log[d * DS + lane]);
    float Dv = Dp[d];
    float vd  = dsh[w][lane];
    float vpx = vd * xsh[w][lane];
    size_t base = ((size_t)bc * DI + d) * 64;
    float h = hstart[base + lane];
    float* Pw = P[w];

    #pragma unroll
    for (int t16 = 0; t16 < 4; ++t16) {
        #pragma unroll
        for (int tt = 0; tt < 16; ++tt) {
            int t = t16 * 16 + tt;
            float2 bcv = *(const float2*)&BCsh[t][2 * lane];
            float dt_ = rdl(vd, t);
            float px  = rdl(vpx, t);
            h = h * __expf(dt_ * a) + px * bcv.x;
            Pw[tt * 69 + lane] = h * bcv.y;
        }
        // per-wave reduce: lane = (q=lane>>4, tr=lane&15); sum over s
        float sacc = 0.f;
        int tr = lane & 15, q = lane >> 4;
        #pragma unroll
        for (int j = 0; j < 16; ++j) sacc += Pw[tr * 69 + q * 16 + j];
        sacc += __shfl_xor(sacc, 16);
        sacc += __shfl_xor(sacc, 32);
        if (lane < 16) {
            int t = t16 * 16 + lane;
            float yv = (sacc + xsh[w][t] * Dv) * silu_f(zsh[w][t]);
            yT[((size_t)(b * DI + d)) * Lseq + c * CH + t] = yv;
        }
    }
}

extern "C" void kernel_launch(void* const* d_in, const int* in_sizes, int n_in,
                              void* d_out, int out_size, void* d_ws, size_t ws_size,
                              hipStream_t stream) {
    const float* frames = (const float*)d_in[0];
    const float* gamma  = (const float*)d_in[1];
    const float* beta   = (const float*)d_in[2];
    const float* W_in   = (const float*)d_in[3];
    const float* conv_w = (const float*)d_in[4];
    const float* conv_b = (const float*)d_in[5];
    const float* W_x    = (const float*)d_in[6];
    const float* W_dt   = (const float*)d_in[7];
    const float* b_dt   = (const float*)d_in[8];
    const float* A_log  = (const float*)d_in[9];
    const float* Dp     = (const float*)d_in[10];
    const float* W_out  = (const float*)d_in[11];
    float* out = (float*)d_out;

    // workspace carve-up (bytes)
    char* ws = (char*)d_ws;
    __hip_bfloat16* xn_bf  = (__hip_bfloat16*)ws; ws += (size_t)NROWS * DM * 2;
    __hip_bfloat16* Wt_in  = (__hip_bfloat16*)ws; ws += (size_t)(2 * DI) * DM * 2;
    __hip_bfloat16* Wt_out = (__hip_bfloat16*)ws; ws += (size_t)DM * DI * 2;
    __hip_bfloat16* Wt_x   = (__hip_bfloat16*)ws; ws += (size_t)XDBW * DI * 2;
    __hip_bfloat16* y_row  = (__hip_bfloat16*)ws; ws += (size_t)NROWS * DI * 2;
    __hip_bfloat16* xcv_bf = (__hip_bfloat16*)ws; ws += (size_t)NROWS * DI * 2;
    float* xz     = (float*)ws;  ws += (size_t)NROWS * 2 * DI * 4;
    float* xcv    = (float*)ws;  ws += (size_t)NROWS * DI * 4;
    float* xdb    = (float*)ws;  ws += (size_t)NROWS * XDBW * 4;
    float* delta  = (float*)ws;  ws += (size_t)NROWS * DI * 4;
    float* yT     = (float*)ws;  ws += (size_t)NROWS * DI * 4;
    float* hend   = (float*)ws;  ws += (size_t)Bn * NC * DI * 64 * 4;
    float* hstart = (float*)ws;  ws += (size_t)Bn * NC * DI * 64 * 4;
    float* dsum   = (float*)ws;  ws += (size_t)Bn * NC * DI * 4;

    // weight cast+transpose
    transpose_cast<<<dim3(2 * DI / 64, DM / 64, 1), 256, 0, stream>>>(W_in, Wt_in, DM, 2 * DI);
    transpose_cast<<<dim3(DM / 64, DI / 64, 1), 256, 0, stream>>>(W_out, Wt_out, DI, DM);
    transpose_cast<<<dim3((XDBW + 63) / 64, DI / 64, 1), 256, 0, stream>>>(W_x, Wt_x, DI, XDBW);

    ln_kernel<<<NROWS, 256, 0, stream>>>(frames, gamma, beta, xn_bf);

    // in_proj: xz = xn @ W_in  (M=2048, N=2048, K=512)
    gemm_bf16<false><<<dim3(2 * DI / 128, NROWS / 128), 256, 0, stream>>>(
        xn_bf, Wt_in, nullptr, xz, NROWS, 2 * DI, DM);

    conv_silu<<<(NROWS * DI) / 256, 256, 0, stream>>>(xz, conv_w, conv_b, xcv, xcv_bf);

    // xdb = xcv @ W_x  (M=2048, N=160, K=1024) via MFMA, guarded N
    gemm_bf16<false><<<dim3((XDBW + 127) / 128, NROWS / 128), 256, 0, stream>>>(
        xcv_bf, Wt_x, nullptr, xdb, NROWS, XDBW, DI);

    delta_kernel<<<dim3(DI / 256, NROWS), 256, 0, stream>>>(xdb, W_dt, b_dt, delta);

    // chunked selective scan
    scan_chunk1<<<Bn * NC * (DI / 8), 512, 0, stream>>>(delta, xcv, xdb, A_log, hend, dsum);
    scan_stitch<<<Bn * DI / 4, 256, 0, stream>>>(hend, dsum, A_log, hstart);
    scan_chunk2<<<Bn * NC * (DI / 8), 512, 0, stream>>>(delta, xcv, xdb, xz, A_log, Dp, hstart, yT);

    // yT [b][1024 d][1024 t] -> y_row bf16 [b*L + t][d]
    transpose_cast<<<dim3(Lseq / 64, DI / 64, Bn), 256, 0, stream>>>(yT, y_row, DI, Lseq);

    // out_proj: out = y_row @ W_out + frames  (M=2048, N=512, K=1024)
    gemm_bf16<true><<<dim3(DM / 128, NROWS / 128), 256, 0, stream>>>(
        y_row, Wt_out, frames, out, NROWS, DM, DI);
}

// Round 8
// 289.744 us; speedup vs baseline: 1.0265x; 1.0265x over previous
//
#include <hip/hip_runtime.h>
#include <hip/hip_bf16.h>
#include <math.h>

// Problem constants
constexpr int Bn     = 2;
constexpr int Lseq   = 1024;
constexpr int DM     = 512;    // d_model
constexpr int DI     = 1024;   // d_inner
constexpr int DS     = 64;     // d_state
constexpr int RNK    = 32;     // dt_rank
constexpr int NROWS  = Bn * Lseq;  // 2048
constexpr int XDBW   = RNK + 2 * DS; // 160
constexpr int CH     = 64;     // scan chunk length
constexpr int NC     = Lseq / CH;  // 16 chunks

typedef __attribute__((ext_vector_type(4))) float floatx4;
typedef __attribute__((ext_vector_type(8))) short shortx8;

__device__ __forceinline__ float silu_f(float v) {
    return v / (1.f + __expf(-v));
}

__device__ __forceinline__ float rdl(float v, int l) {
    return __int_as_float(__builtin_amdgcn_readlane(__float_as_int(v), l));
}

// ---------------- LayerNorm -> bf16 ----------------
__global__ void ln_kernel(const float* __restrict__ x, const float* __restrict__ g,
                          const float* __restrict__ be, __hip_bfloat16* __restrict__ xn) {
    int row = blockIdx.x;
    int tid = threadIdx.x;
    const float* xr = x + (size_t)row * DM;
    float v0 = xr[tid], v1 = xr[tid + 256];
    float s = v0 + v1, sq = v0 * v0 + v1 * v1;
    #pragma unroll
    for (int o = 1; o < 64; o <<= 1) {
        s  += __shfl_xor(s, o);
        sq += __shfl_xor(sq, o);
    }
    __shared__ float red[8];
    int w = tid >> 6;
    if ((tid & 63) == 0) { red[w] = s; red[4 + w] = sq; }
    __syncthreads();
    float ts = red[0] + red[1] + red[2] + red[3];
    float tq = red[4] + red[5] + red[6] + red[7];
    float mu  = ts * (1.f / DM);
    float var = tq * (1.f / DM) - mu * mu;
    float inv = rsqrtf(var + 1e-5f);
    __hip_bfloat16* o0 = xn + (size_t)row * DM;
    o0[tid]       = __float2bfloat16((v0 - mu) * inv * g[tid]       + be[tid]);
    o0[tid + 256] = __float2bfloat16((v1 - mu) * inv * g[tid + 256] + be[tid + 256]);
}

// ---------------- Transpose + cast: in fp32 [R][Cc] -> out bf16 [Cc][R], bounds-guarded ----
__global__ void transpose_cast(const float* __restrict__ in, __hip_bfloat16* __restrict__ out,
                               int R, int Cc) {
    __shared__ float tile[64][65];
    const float* inb = in + (size_t)blockIdx.z * R * Cc;
    __hip_bfloat16* outb = out + (size_t)blockIdx.z * R * Cc;
    int r0 = blockIdx.y * 64, c0 = blockIdx.x * 64;
    int tid = threadIdx.x;
    #pragma unroll
    for (int i = tid; i < 4096; i += 256) {
        int r = i >> 6, c = i & 63;
        tile[r][c] = (r0 + r < R && c0 + c < Cc) ? inb[(size_t)(r0 + r) * Cc + c0 + c] : 0.f;
    }
    __syncthreads();
    #pragma unroll
    for (int i = tid; i < 4096; i += 256) {
        int c = i >> 6, r = i & 63;
        if (r0 + r < R && c0 + c < Cc)
            outb[(size_t)(c0 + c) * R + r0 + r] = __float2bfloat16(tile[r][c]);
    }
}

// ---------------- bf16 MFMA GEMM: C(MxN) = A(MxK) * Bt(NxK)^T  [+ Res] ----------------
template<bool RES>
__global__ __launch_bounds__(256) void gemm_bf16(const __hip_bfloat16* __restrict__ A,
                                                 const __hip_bfloat16* __restrict__ Bt,
                                                 const float* __restrict__ Res,
                                                 float* __restrict__ C,
                                                 int M, int N, int K) {
    __shared__ __hip_bfloat16 As[128 * 32];
    __shared__ __hip_bfloat16 Bs[128 * 32];
    const int tid  = threadIdx.x;
    const int wave = tid >> 6, lane = tid & 63;
    const int m0 = blockIdx.y * 128, n0 = blockIdx.x * 128;
    const int wm = (wave >> 1) * 64, wn = (wave & 1) * 64;

    floatx4 acc[4][4] = {};

    const int arow16 = lane & 15;
    const int kgrp   = lane >> 4;

    for (int k0 = 0; k0 < K; k0 += 32) {
        #pragma unroll
        for (int r = 0; r < 2; ++r) {
            int i   = wave * 64 + r * 256 + lane;   // 0..511
            int row = i >> 2, seg = i & 3;
            int brow = n0 + row; if (brow >= N) brow = N - 1;
            const __hip_bfloat16* gA = A  + (size_t)(m0 + row) * K + k0 + seg * 8;
            const __hip_bfloat16* gB = Bt + (size_t)brow * K + k0 + seg * 8;
            __hip_bfloat16* lA = As + (size_t)(wave * 64 + r * 256) * 8;
            __hip_bfloat16* lB = Bs + (size_t)(wave * 64 + r * 256) * 8;
            __builtin_amdgcn_global_load_lds(
                (const __attribute__((address_space(1))) void*)gA,
                (__attribute__((address_space(3))) void*)lA, 16, 0, 0);
            __builtin_amdgcn_global_load_lds(
                (const __attribute__((address_space(1))) void*)gB,
                (__attribute__((address_space(3))) void*)lB, 16, 0, 0);
        }
        __syncthreads();

        const shortx8* Asv = (const shortx8*)As;
        const shortx8* Bsv = (const shortx8*)Bs;
        shortx8 a[4], b[4];
        #pragma unroll
        for (int i = 0; i < 4; ++i)
            a[i] = Asv[(wm + i * 16 + arow16) * 4 + kgrp];
        #pragma unroll
        for (int j = 0; j < 4; ++j)
            b[j] = Bsv[(wn + j * 16 + arow16) * 4 + kgrp];
        #pragma unroll
        for (int i = 0; i < 4; ++i)
            #pragma unroll
            for (int j = 0; j < 4; ++j)
                acc[i][j] = __builtin_amdgcn_mfma_f32_16x16x32_bf16(a[i], b[j], acc[i][j], 0, 0, 0);
        __syncthreads();
    }

    const int drow = (lane >> 4) * 4;
    const int dcol = lane & 15;
    #pragma unroll
    for (int i = 0; i < 4; ++i)
        #pragma unroll
        for (int j = 0; j < 4; ++j) {
            int rowb = m0 + wm + i * 16 + drow;
            int col  = n0 + wn + j * 16 + dcol;
            if (col < N) {
                #pragma unroll
                for (int r = 0; r < 4; ++r) {
                    size_t idx = (size_t)(rowb + r) * N + col;
                    float v = acc[i][j][r];
                    if (RES) v += Res[idx];
                    C[idx] = v;
                }
            }
        }
}

// ---------------- Causal depthwise conv (taps=4) + bias + SiLU, dual fp32/bf16 out -------
__global__ void conv_silu(const float* __restrict__ xz, const float* __restrict__ cw,
                          const float* __restrict__ cb, float* __restrict__ xcv,
                          __hip_bfloat16* __restrict__ xcv_bf) {
    int idx = blockIdx.x * 256 + threadIdx.x;   // (b*L + t)*DI + d
    int d = idx & (DI - 1);
    int bt = idx / DI;
    int t = bt & (Lseq - 1);
    int b = bt / Lseq;
    float acc = cb[d];
    #pragma unroll
    for (int k = 0; k < 4; ++k) {
        int tt = t - 3 + k;
        float xv = (tt >= 0) ? xz[((size_t)(b * Lseq + tt)) * (2 * DI) + d] : 0.f;
        acc += xv * cw[d * 4 + k];
    }
    float v = silu_f(acc);
    xcv[idx] = v;
    xcv_bf[idx] = __float2bfloat16(v);
}

// ---------------- delta = softplus(dt @ W_dt + b_dt) ----------------
__global__ void delta_kernel(const float* __restrict__ xdb, const float* __restrict__ Wdt,
                             const float* __restrict__ bdt, float* __restrict__ delta) {
    int row = blockIdx.y;
    int d = blockIdx.x * 256 + threadIdx.x;
    __shared__ float dtv[RNK];
    if (threadIdx.x < RNK) dtv[threadIdx.x] = xdb[(size_t)row * XDBW + threadIdx.x];
    __syncthreads();
    float acc = bdt[d];
    #pragma unroll
    for (int r = 0; r < RNK; ++r) acc += dtv[r] * Wdt[(size_t)r * DI + d];
    float sp = (acc > 20.f) ? acc : log1pf(__expf(acc));
    delta[(size_t)row * DI + d] = sp;
}

// ============ Chunked scan, phase 1: local scan per chunk (h0=0) + chunk delta-sum =======
// (unchanged from round 6/7 — proven correct)
__global__ __launch_bounds__(512) void scan_chunk1(
        const float* __restrict__ delta, const float* __restrict__ xcv,
        const float* __restrict__ xdb, const float* __restrict__ A_log,
        float* __restrict__ hend, float* __restrict__ dsum) {
    __shared__ float Bsh[64][68];
    __shared__ float dsh[8][64];
    __shared__ float xsh[8][64];

    int blk = blockIdx.x;
    int dg  = blk & (DI / 8 - 1);   // 0..127
    int bc  = blk >> 7;             // b*NC + c
    int c = bc & (NC - 1), b = bc >> 4;
    int tid = threadIdx.x, w = tid >> 6, lane = tid & 63;
    int d = dg * 8 + w;
    int r0 = b * Lseq + c * CH;

    // stage B (cols 32..95 of xdb), float4
    #pragma unroll
    for (int k = 0; k < 2; ++k) {
        int idx = tid + k * 512;          // 0..1023
        int row = idx >> 4, j4 = idx & 15;
        float4 v = *(const float4*)&xdb[(size_t)(r0 + row) * XDBW + RNK + j4 * 4];
        *(float4*)&Bsh[row][j4 * 4] = v;
    }
    {
        int t = tid >> 3, ww = tid & 7;
        dsh[ww][t] = delta[(size_t)(r0 + t) * DI + dg * 8 + ww];
        xsh[ww][t] = xcv[(size_t)(r0 + t) * DI + dg * 8 + ww];
    }
    __syncthreads();

    float a = -__expf(A_log[d * DS + lane]);
    float vd  = dsh[w][lane];           // delta for t=lane
    float vpx = vd * xsh[w][lane];      // delta*x for t=lane
    float h = 0.f;
    #pragma unroll 16
    for (int t = 0; t < CH; ++t) {
        float dt_ = rdl(vd, t);
        float px  = rdl(vpx, t);
        h = h * __expf(dt_ * a) + px * Bsh[t][lane];
    }
    float S = vd;
    #pragma unroll
    for (int o = 1; o < 64; o <<= 1) S += __shfl_xor(S, o);
    size_t base = ((size_t)bc * DI + d) * 64;
    hend[base + lane] = h;
    if (lane == 0) dsum[(size_t)bc * DI + d] = S;
}

// ============ Chunked scan, phase 2: stitch across chunks ============
__global__ __launch_bounds__(256) void scan_stitch(
        const float* __restrict__ hend, const float* __restrict__ dsum,
        const float* __restrict__ A_log, float* __restrict__ hstart) {
    int idx = blockIdx.x * 4 + (threadIdx.x >> 6);   // b*DI + d
    int lane = threadIdx.x & 63;
    int b = idx >> 10, d = idx & (DI - 1);
    float a = -__expf(A_log[d * DS + lane]);
    float h = 0.f;
    #pragma unroll
    for (int c = 0; c < NC; ++c) {
        size_t base = ((size_t)(b * NC + c) * DI + d) * 64;
        hstart[base + lane] = h;
        float he = hend[base + lane];
        float S  = dsum[(size_t)(b * NC + c) * DI + d];
        h = he + __expf(a * S) * h;
    }
}

// ============ Chunked scan, phase 3 ============
// LDS diet for occupancy: BC packed bf16 (one dword = C|B per (t,s)) 16.6 KB,
// P batched per 8 t (stride 65) 16.6 KB, d/x/z 6 KB -> 38.5 KB -> 4 blocks/CU.
// All LDS patterns <=2-way (free): BC read = 64 consecutive dwords; P write
// stride-1; P read bank (tr+8q+j)%32 = 2-way; reduce tail = 3x shfl_xor.
__global__ __launch_bounds__(512) void scan_chunk2(
        const float* __restrict__ delta, const float* __restrict__ xcv,
        const float* __restrict__ xdb, const float* __restrict__ xz,
        const float* __restrict__ A_log, const float* __restrict__ Dp,
        const float* __restrict__ hstart, float* __restrict__ yT) {
    __shared__ unsigned int BCsh[64][65];  // [t][s] = (C & 0xFFFF0000) | (B >> 16)
    __shared__ float dsh[8][64];
    __shared__ float xsh[8][64];
    __shared__ float zsh[8][64];
    __shared__ float P[8][8 * 65];

    int blk = blockIdx.x;
    int dg  = blk & (DI / 8 - 1);
    int bc  = blk >> 7;
    int c = bc & (NC - 1), b = bc >> 4;
    int tid = threadIdx.x, w = tid >> 6, lane = tid & 63;
    int d = dg * 8 + w;
    int r0 = b * Lseq + c * CH;

    // stage BC packed: thread handles (t, s-group of 4); b128 write, 2-way max
    #pragma unroll
    for (int k = 0; k < 2; ++k) {
        int i = tid + k * 512;            // 0..1023
        int t = i >> 4, sg = i & 15;
        const float* rowp = &xdb[(size_t)(r0 + t) * XDBW + RNK];
        float4 bv = *(const float4*)&rowp[sg * 4];
        float4 cv = *(const float4*)&rowp[DS + sg * 4];
        uint4 pk;
        #pragma unroll
        for (int j = 0; j < 4; ++j) {
            unsigned int bb = __float_as_uint((&bv.x)[j]);
            unsigned int cc2 = __float_as_uint((&cv.x)[j]);
            (&pk.x)[j] = (cc2 & 0xFFFF0000u) | (bb >> 16);
        }
        *(uint4*)&BCsh[t][sg * 4] = pk;
    }
    {
        int t = tid >> 3, ww = tid & 7;
        dsh[ww][t] = delta[(size_t)(r0 + t) * DI + dg * 8 + ww];
        xsh[ww][t] = xcv[(size_t)(r0 + t) * DI + dg * 8 + ww];
        zsh[ww][t] = xz[(size_t)(r0 + t) * (2 * DI) + DI + dg * 8 + ww];
    }
    __syncthreads();

    float a  = -__expf(A_log[d * DS + lane]);
    float Dv = Dp[d];
    float vd  = dsh[w][lane];
    float vpx = vd * xsh[w][lane];
    float h = hstart[((size_t)bc * DI + d) * 64 + lane];
    float* Pw = P[w];
    float yreg = 0.f;
    const int tr = lane & 7, q = lane >> 3;

    #pragma unroll
    for (int t8 = 0; t8 < 8; ++t8) {
        #pragma unroll
        for (int tt = 0; tt < 8; ++tt) {
            int t = t8 * 8 + tt;
            unsigned int bcp = BCsh[t][lane];
            float Bt = __uint_as_float(bcp << 16);
            float Ct = __uint_as_float(bcp & 0xFFFF0000u);
            float dt_ = rdl(vd, t);
            float px  = rdl(vpx, t);
            h = h * __expf(dt_ * a) + px * Bt;
            Pw[tt * 65 + lane] = h * Ct;
        }
        // reduce: lane (q = s-octet, tr = t-in-batch); 8 partials then 3 shuffles
        float sacc = 0.f;
        #pragma unroll
        for (int j = 0; j < 8; ++j) sacc += Pw[tr * 65 + q * 8 + j];
        sacc += __shfl_xor(sacc, 8);
        sacc += __shfl_xor(sacc, 16);
        sacc += __shfl_xor(sacc, 32);
        if (q == t8) yreg = sacc;   // lane l owns t = l  (l = t8*8 + tr)
    }

    float yv = (yreg + xsh[w][lane] * Dv) * silu_f(zsh[w][lane]);
    yT[((size_t)(b * DI + d)) * Lseq + c * CH + lane] = yv;
}

extern "C" void kernel_launch(void* const* d_in, const int* in_sizes, int n_in,
                              void* d_out, int out_size, void* d_ws, size_t ws_size,
                              hipStream_t stream) {
    const float* frames = (const float*)d_in[0];
    const float* gamma  = (const float*)d_in[1];
    const float* beta   = (const float*)d_in[2];
    const float* W_in   = (const float*)d_in[3];
    const float* conv_w = (const float*)d_in[4];
    const float* conv_b = (const float*)d_in[5];
    const float* W_x    = (const float*)d_in[6];
    const float* W_dt   = (const float*)d_in[7];
    const float* b_dt   = (const float*)d_in[8];
    const float* A_log  = (const float*)d_in[9];
    const float* Dp     = (const float*)d_in[10];
    const float* W_out  = (const float*)d_in[11];
    float* out = (float*)d_out;

    // workspace carve-up (bytes)
    char* ws = (char*)d_ws;
    __hip_bfloat16* xn_bf  = (__hip_bfloat16*)ws; ws += (size_t)NROWS * DM * 2;
    __hip_bfloat16* Wt_in  = (__hip_bfloat16*)ws; ws += (size_t)(2 * DI) * DM * 2;
    __hip_bfloat16* Wt_out = (__hip_bfloat16*)ws; ws += (size_t)DM * DI * 2;
    __hip_bfloat16* Wt_x   = (__hip_bfloat16*)ws; ws += (size_t)XDBW * DI * 2;
    __hip_bfloat16* y_row  = (__hip_bfloat16*)ws; ws += (size_t)NROWS * DI * 2;
    __hip_bfloat16* xcv_bf = (__hip_bfloat16*)ws; ws += (size_t)NROWS * DI * 2;
    float* xz     = (float*)ws;  ws += (size_t)NROWS * 2 * DI * 4;
    float* xcv    = (float*)ws;  ws += (size_t)NROWS * DI * 4;
    float* xdb    = (float*)ws;  ws += (size_t)NROWS * XDBW * 4;
    float* delta  = (float*)ws;  ws += (size_t)NROWS * DI * 4;
    float* yT     = (float*)ws;  ws += (size_t)NROWS * DI * 4;
    float* hend   = (float*)ws;  ws += (size_t)Bn * NC * DI * 64 * 4;
    float* hstart = (float*)ws;  ws += (size_t)Bn * NC * DI * 64 * 4;
    float* dsum   = (float*)ws;  ws += (size_t)Bn * NC * DI * 4;

    // weight cast+transpose
    transpose_cast<<<dim3(2 * DI / 64, DM / 64, 1), 256, 0, stream>>>(W_in, Wt_in, DM, 2 * DI);
    transpose_cast<<<dim3(DM / 64, DI / 64, 1), 256, 0, stream>>>(W_out, Wt_out, DI, DM);
    transpose_cast<<<dim3((XDBW + 63) / 64, DI / 64, 1), 256, 0, stream>>>(W_x, Wt_x, DI, XDBW);

    ln_kernel<<<NROWS, 256, 0, stream>>>(frames, gamma, beta, xn_bf);

    // in_proj: xz = xn @ W_in  (M=2048, N=2048, K=512)
    gemm_bf16<false><<<dim3(2 * DI / 128, NROWS / 128), 256, 0, stream>>>(
        xn_bf, Wt_in, nullptr, xz, NROWS, 2 * DI, DM);

    conv_silu<<<(NROWS * DI) / 256, 256, 0, stream>>>(xz, conv_w, conv_b, xcv, xcv_bf);

    // xdb = xcv @ W_x  (M=2048, N=160, K=1024) via MFMA, guarded N
    gemm_bf16<false><<<dim3((XDBW + 127) / 128, NROWS / 128), 256, 0, stream>>>(
        xcv_bf, Wt_x, nullptr, xdb, NROWS, XDBW, DI);

    delta_kernel<<<dim3(DI / 256, NROWS), 256, 0, stream>>>(xdb, W_dt, b_dt, delta);

    // chunked selective scan
    scan_chunk1<<<Bn * NC * (DI / 8), 512, 0, stream>>>(delta, xcv, xdb, A_log, hend, dsum);
    scan_stitch<<<Bn * DI / 4, 256, 0, stream>>>(hend, dsum, A_log, hstart);
    scan_chunk2<<<Bn * NC * (DI / 8), 512, 0, stream>>>(delta, xcv, xdb, xz, A_log, Dp, hstart, yT);

    // yT [b][1024 d][1024 t] -> y_row bf16 [b*L + t][d]
    transpose_cast<<<dim3(Lseq / 64, DI / 64, Bn), 256, 0, stream>>>(yT, y_row, DI, Lseq);

    // out_proj: out = y_row @ W_out + frames  (M=2048, N=512, K=1024)
    gemm_bf16<true><<<dim3(DM / 128, NROWS / 128), 256, 0, stream>>>(
        y_row, Wt_out, frames, out, NROWS, DM, DI);
}

// Round 9
// 246.923 us; speedup vs baseline: 1.2045x; 1.1734x over previous
//
#include <hip/hip_runtime.h>
#include <hip/hip_bf16.h>
#include <math.h>

// Problem constants
constexpr int Bn     = 2;
constexpr int Lseq   = 1024;
constexpr int DM     = 512;    // d_model
constexpr int DI     = 1024;   // d_inner
constexpr int DS     = 64;     // d_state
constexpr int RNK    = 32;     // dt_rank
constexpr int NROWS  = Bn * Lseq;  // 2048
constexpr int XDBW   = RNK + 2 * DS; // 160
constexpr int CH     = 64;     // scan chunk length
constexpr int NC     = Lseq / CH;  // 16 chunks

typedef __attribute__((ext_vector_type(4))) float floatx4;
typedef __attribute__((ext_vector_type(8))) short shortx8;

__device__ __forceinline__ float silu_f(float v) {
    return v / (1.f + __expf(-v));
}

__device__ __forceinline__ float rdl(float v, int l) {
    return __int_as_float(__builtin_amdgcn_readlane(__float_as_int(v), l));
}

// ---------------- LayerNorm -> bf16 ----------------
__global__ void ln_kernel(const float* __restrict__ x, const float* __restrict__ g,
                          const float* __restrict__ be, __hip_bfloat16* __restrict__ xn) {
    int row = blockIdx.x;
    int tid = threadIdx.x;
    const float* xr = x + (size_t)row * DM;
    float v0 = xr[tid], v1 = xr[tid + 256];
    float s = v0 + v1, sq = v0 * v0 + v1 * v1;
    #pragma unroll
    for (int o = 1; o < 64; o <<= 1) {
        s  += __shfl_xor(s, o);
        sq += __shfl_xor(sq, o);
    }
    __shared__ float red[8];
    int w = tid >> 6;
    if ((tid & 63) == 0) { red[w] = s; red[4 + w] = sq; }
    __syncthreads();
    float ts = red[0] + red[1] + red[2] + red[3];
    float tq = red[4] + red[5] + red[6] + red[7];
    float mu  = ts * (1.f / DM);
    float var = tq * (1.f / DM) - mu * mu;
    float inv = rsqrtf(var + 1e-5f);
    __hip_bfloat16* o0 = xn + (size_t)row * DM;
    o0[tid]       = __float2bfloat16((v0 - mu) * inv * g[tid]       + be[tid]);
    o0[tid + 256] = __float2bfloat16((v1 - mu) * inv * g[tid + 256] + be[tid + 256]);
}

// ---------------- Fused 3-way weight transpose+cast (one launch) ----------------
// blocks [0,256): W_in 512x2048 ; [256,384): W_out 1024x512 ; [384,432): W_x 1024x160
__global__ void transpose_cast3(const float* __restrict__ Wi, const float* __restrict__ Wo,
                                const float* __restrict__ Wx,
                                __hip_bfloat16* __restrict__ Ti, __hip_bfloat16* __restrict__ To,
                                __hip_bfloat16* __restrict__ Tx) {
    __shared__ float tile[64][65];
    int bid = blockIdx.x;
    const float* in; __hip_bfloat16* out; int R, Cc, bx, by;
    if (bid < 256)      { in = Wi; out = Ti; R = DM; Cc = 2 * DI; bx = bid & 31;        by = bid >> 5; }
    else if (bid < 384) { int b2 = bid - 256; in = Wo; out = To; R = DI; Cc = DM;   bx = b2 & 7;  by = b2 >> 3; }
    else                { int b2 = bid - 384; in = Wx; out = Tx; R = DI; Cc = XDBW; bx = b2 % 3;  by = b2 / 3; }
    int r0 = by * 64, c0 = bx * 64;
    int tid = threadIdx.x;
    #pragma unroll
    for (int i = tid; i < 4096; i += 256) {
        int r = i >> 6, c = i & 63;
        tile[r][c] = (r0 + r < R && c0 + c < Cc) ? in[(size_t)(r0 + r) * Cc + c0 + c] : 0.f;
    }
    __syncthreads();
    #pragma unroll
    for (int i = tid; i < 4096; i += 256) {
        int c = i >> 6, r = i & 63;
        if (r0 + r < R && c0 + c < Cc)
            out[(size_t)(c0 + c) * R + r0 + r] = __float2bfloat16(tile[r][c]);
    }
}

// ---------------- bf16 MFMA GEMM 128x128 tile (for in_proj) ----------------
template<bool RES>
__global__ __launch_bounds__(256) void gemm_bf16(const __hip_bfloat16* __restrict__ A,
                                                 const __hip_bfloat16* __restrict__ Bt,
                                                 const float* __restrict__ Res,
                                                 float* __restrict__ C,
                                                 int M, int N, int K) {
    __shared__ __hip_bfloat16 As[128 * 32];
    __shared__ __hip_bfloat16 Bs[128 * 32];
    const int tid  = threadIdx.x;
    const int wave = tid >> 6, lane = tid & 63;
    const int m0 = blockIdx.y * 128, n0 = blockIdx.x * 128;
    const int wm = (wave >> 1) * 64, wn = (wave & 1) * 64;

    floatx4 acc[4][4] = {};

    const int arow16 = lane & 15;
    const int kgrp   = lane >> 4;

    for (int k0 = 0; k0 < K; k0 += 32) {
        #pragma unroll
        for (int r = 0; r < 2; ++r) {
            int i   = wave * 64 + r * 256 + lane;   // 0..511
            int row = i >> 2, seg = i & 3;
            int brow = n0 + row; if (brow >= N) brow = N - 1;
            const __hip_bfloat16* gA = A  + (size_t)(m0 + row) * K + k0 + seg * 8;
            const __hip_bfloat16* gB = Bt + (size_t)brow * K + k0 + seg * 8;
            __hip_bfloat16* lA = As + (size_t)(wave * 64 + r * 256) * 8;
            __hip_bfloat16* lB = Bs + (size_t)(wave * 64 + r * 256) * 8;
            __builtin_amdgcn_global_load_lds(
                (const __attribute__((address_space(1))) void*)gA,
                (__attribute__((address_space(3))) void*)lA, 16, 0, 0);
            __builtin_amdgcn_global_load_lds(
                (const __attribute__((address_space(1))) void*)gB,
                (__attribute__((address_space(3))) void*)lB, 16, 0, 0);
        }
        __syncthreads();

        const shortx8* Asv = (const shortx8*)As;
        const shortx8* Bsv = (const shortx8*)Bs;
        shortx8 a[4], b[4];
        #pragma unroll
        for (int i = 0; i < 4; ++i)
            a[i] = Asv[(wm + i * 16 + arow16) * 4 + kgrp];
        #pragma unroll
        for (int j = 0; j < 4; ++j)
            b[j] = Bsv[(wn + j * 16 + arow16) * 4 + kgrp];
        #pragma unroll
        for (int i = 0; i < 4; ++i)
            #pragma unroll
            for (int j = 0; j < 4; ++j)
                acc[i][j] = __builtin_amdgcn_mfma_f32_16x16x32_bf16(a[i], b[j], acc[i][j], 0, 0, 0);
        __syncthreads();
    }

    const int drow = (lane >> 4) * 4;
    const int dcol = lane & 15;
    #pragma unroll
    for (int i = 0; i < 4; ++i)
        #pragma unroll
        for (int j = 0; j < 4; ++j) {
            int rowb = m0 + wm + i * 16 + drow;
            int col  = n0 + wn + j * 16 + dcol;
            if (col < N) {
                #pragma unroll
                for (int r = 0; r < 4; ++r) {
                    size_t idx = (size_t)(rowb + r) * N + col;
                    float v = acc[i][j][r];
                    if (RES) v += Res[idx];
                    C[idx] = v;
                }
            }
        }
}

// ---------------- bf16 MFMA GEMM 64x64 tile (small-N GEMMs: more blocks) ----------------
// 256 thr = 4 waves in 2x2, each wave 32x32 (2x2 MFMA 16x16x32), BK=32.
// Same staging/frag bank pattern as the 128-tile kernel (2-way max).
template<bool RES>
__global__ __launch_bounds__(256) void gemm_bf16_64(const __hip_bfloat16* __restrict__ A,
                                                    const __hip_bfloat16* __restrict__ Bt,
                                                    const float* __restrict__ Res,
                                                    float* __restrict__ C,
                                                    int M, int N, int K) {
    __shared__ __hip_bfloat16 As[64 * 32];
    __shared__ __hip_bfloat16 Bs[64 * 32];
    const int tid  = threadIdx.x;
    const int wave = tid >> 6, lane = tid & 63;
    const int m0 = blockIdx.y * 64, n0 = blockIdx.x * 64;
    const int wm = (wave >> 1) * 32, wn = (wave & 1) * 32;

    floatx4 acc[2][2] = {};

    const int arow16 = lane & 15;
    const int kgrp   = lane >> 4;

    for (int k0 = 0; k0 < K; k0 += 32) {
        {
            int i   = wave * 64 + lane;   // 0..255
            int row = i >> 2, seg = i & 3;
            int brow = n0 + row; if (brow >= N) brow = N - 1;
            const __hip_bfloat16* gA = A  + (size_t)(m0 + row) * K + k0 + seg * 8;
            const __hip_bfloat16* gB = Bt + (size_t)brow * K + k0 + seg * 8;
            __hip_bfloat16* lA = As + (size_t)(wave * 64) * 8;   // wave-uniform base
            __hip_bfloat16* lB = Bs + (size_t)(wave * 64) * 8;
            __builtin_amdgcn_global_load_lds(
                (const __attribute__((address_space(1))) void*)gA,
                (__attribute__((address_space(3))) void*)lA, 16, 0, 0);
            __builtin_amdgcn_global_load_lds(
                (const __attribute__((address_space(1))) void*)gB,
                (__attribute__((address_space(3))) void*)lB, 16, 0, 0);
        }
        __syncthreads();

        const shortx8* Asv = (const shortx8*)As;
        const shortx8* Bsv = (const shortx8*)Bs;
        shortx8 a[2], b[2];
        #pragma unroll
        for (int i = 0; i < 2; ++i)
            a[i] = Asv[(wm + i * 16 + arow16) * 4 + kgrp];
        #pragma unroll
        for (int j = 0; j < 2; ++j)
            b[j] = Bsv[(wn + j * 16 + arow16) * 4 + kgrp];
        #pragma unroll
        for (int i = 0; i < 2; ++i)
            #pragma unroll
            for (int j = 0; j < 2; ++j)
                acc[i][j] = __builtin_amdgcn_mfma_f32_16x16x32_bf16(a[i], b[j], acc[i][j], 0, 0, 0);
        __syncthreads();
    }

    const int drow = (lane >> 4) * 4;
    const int dcol = lane & 15;
    #pragma unroll
    for (int i = 0; i < 2; ++i)
        #pragma unroll
        for (int j = 0; j < 2; ++j) {
            int rowb = m0 + wm + i * 16 + drow;
            int col  = n0 + wn + j * 16 + dcol;
            if (col < N) {
                #pragma unroll
                for (int r = 0; r < 4; ++r) {
                    size_t idx = (size_t)(rowb + r) * N + col;
                    float v = acc[i][j][r];
                    if (RES) v += Res[idx];
                    C[idx] = v;
                }
            }
        }
}

// ---------------- Causal depthwise conv (taps=4) + bias + SiLU, dual fp32/bf16 out -------
__global__ void conv_silu(const float* __restrict__ xz, const float* __restrict__ cw,
                          const float* __restrict__ cb, float* __restrict__ xcv,
                          __hip_bfloat16* __restrict__ xcv_bf) {
    int idx = blockIdx.x * 256 + threadIdx.x;   // (b*L + t)*DI + d
    int d = idx & (DI - 1);
    int bt = idx / DI;
    int t = bt & (Lseq - 1);
    int b = bt / Lseq;
    float acc = cb[d];
    #pragma unroll
    for (int k = 0; k < 4; ++k) {
        int tt = t - 3 + k;
        float xv = (tt >= 0) ? xz[((size_t)(b * Lseq + tt)) * (2 * DI) + d] : 0.f;
        acc += xv * cw[d * 4 + k];
    }
    float v = silu_f(acc);
    xcv[idx] = v;
    xcv_bf[idx] = __float2bfloat16(v);
}

// ---------------- delta = softplus(dt @ W_dt + b_dt) ----------------
__global__ void delta_kernel(const float* __restrict__ xdb, const float* __restrict__ Wdt,
                             const float* __restrict__ bdt, float* __restrict__ delta) {
    int row = blockIdx.y;
    int d = blockIdx.x * 256 + threadIdx.x;
    __shared__ float dtv[RNK];
    if (threadIdx.x < RNK) dtv[threadIdx.x] = xdb[(size_t)row * XDBW + threadIdx.x];
    __syncthreads();
    float acc = bdt[d];
    #pragma unroll
    for (int r = 0; r < RNK; ++r) acc += dtv[r] * Wdt[(size_t)r * DI + d];
    float sp = (acc > 20.f) ? acc : log1pf(__expf(acc));
    delta[(size_t)row * DI + d] = sp;
}

// ============ Chunked scan, phase 1: local scan per chunk (h0=0) + chunk delta-sum =======
__global__ __launch_bounds__(512) void scan_chunk1(
        const float* __restrict__ delta, const float* __restrict__ xcv,
        const float* __restrict__ xdb, const float* __restrict__ A_log,
        float* __restrict__ hend, float* __restrict__ dsum) {
    __shared__ float Bsh[64][68];
    __shared__ float dsh[8][64];
    __shared__ float xsh[8][64];

    int blk = blockIdx.x;
    int dg  = blk & (DI / 8 - 1);   // 0..127
    int bc  = blk >> 7;             // b*NC + c
    int c = bc & (NC - 1), b = bc >> 4;
    int tid = threadIdx.x, w = tid >> 6, lane = tid & 63;
    int d = dg * 8 + w;
    int r0 = b * Lseq + c * CH;

    // stage B (cols 32..95 of xdb), float4
    #pragma unroll
    for (int k = 0; k < 2; ++k) {
        int idx = tid + k * 512;          // 0..1023
        int row = idx >> 4, j4 = idx & 15;
        float4 v = *(const float4*)&xdb[(size_t)(r0 + row) * XDBW + RNK + j4 * 4];
        *(float4*)&Bsh[row][j4 * 4] = v;
    }
    {
        int t = tid >> 3, ww = tid & 7;
        dsh[ww][t] = delta[(size_t)(r0 + t) * DI + dg * 8 + ww];
        xsh[ww][t] = xcv[(size_t)(r0 + t) * DI + dg * 8 + ww];
    }
    __syncthreads();

    float a = -__expf(A_log[d * DS + lane]);
    float vd  = dsh[w][lane];           // delta for t=lane
    float vpx = vd * xsh[w][lane];      // delta*x for t=lane
    float h = 0.f;
    #pragma unroll 16
    for (int t = 0; t < CH; ++t) {
        float dt_ = rdl(vd, t);
        float px  = rdl(vpx, t);
        h = h * __expf(dt_ * a) + px * Bsh[t][lane];
    }
    float S = vd;
    #pragma unroll
    for (int o = 1; o < 64; o <<= 1) S += __shfl_xor(S, o);
    size_t base = ((size_t)bc * DI + d) * 64;
    hend[base + lane] = h;
    if (lane == 0) dsum[(size_t)bc * DI + d] = S;
}

// ============ Chunked scan, phase 2: stitch across chunks ============
__global__ __launch_bounds__(256) void scan_stitch(
        const float* __restrict__ hend, const float* __restrict__ dsum,
        const float* __restrict__ A_log, float* __restrict__ hstart) {
    int idx = blockIdx.x * 4 + (threadIdx.x >> 6);   // b*DI + d
    int lane = threadIdx.x & 63;
    int b = idx >> 10, d = idx & (DI - 1);
    float a = -__expf(A_log[d * DS + lane]);
    float h = 0.f;
    #pragma unroll
    for (int c = 0; c < NC; ++c) {
        size_t base = ((size_t)(b * NC + c) * DI + d) * 64;
        hstart[base + lane] = h;
        float he = hend[base + lane];
        float S  = dsum[(size_t)(b * NC + c) * DI + d];
        h = he + __expf(a * S) * h;
    }
}

// ============ Chunked scan, phase 3: recompute with h_start, emit gated y_row bf16 ======
// BC packed bf16 16.6 KB + P (8x8x65) 16.6 KB + d/x/z 6 KB -> 4 blocks/CU.
// Epilogue: block-wide 64x8 transpose (reusing P) -> direct bf16 y_row store.
__global__ __launch_bounds__(512) void scan_chunk2(
        const float* __restrict__ delta, const float* __restrict__ xcv,
        const float* __restrict__ xdb, const float* __restrict__ xz,
        const float* __restrict__ A_log, const float* __restrict__ Dp,
        const float* __restrict__ hstart, __hip_bfloat16* __restrict__ y_row) {
    __shared__ unsigned int BCsh[64][65];  // [t][s] = (C & 0xFFFF0000) | (B >> 16)
    __shared__ float dsh[8][64];
    __shared__ float xsh[8][64];
    __shared__ float zsh[8][64];
    __shared__ float P[8][8 * 65];

    int blk = blockIdx.x;
    int dg  = blk & (DI / 8 - 1);
    int bc  = blk >> 7;
    int c = bc & (NC - 1), b = bc >> 4;
    int tid = threadIdx.x, w = tid >> 6, lane = tid & 63;
    int d = dg * 8 + w;
    int r0 = b * Lseq + c * CH;

    // stage BC packed: thread handles (t, s-group of 4); b128 write, 2-way max
    #pragma unroll
    for (int k = 0; k < 2; ++k) {
        int i = tid + k * 512;            // 0..1023
        int t = i >> 4, sg = i & 15;
        const float* rowp = &xdb[(size_t)(r0 + t) * XDBW + RNK];
        float4 bv = *(const float4*)&rowp[sg * 4];
        float4 cv = *(const float4*)&rowp[DS + sg * 4];
        uint4 pk;
        #pragma unroll
        for (int j = 0; j < 4; ++j) {
            unsigned int bb = __float_as_uint((&bv.x)[j]);
            unsigned int cc2 = __float_as_uint((&cv.x)[j]);
            (&pk.x)[j] = (cc2 & 0xFFFF0000u) | (bb >> 16);
        }
        *(uint4*)&BCsh[t][sg * 4] = pk;
    }
    {
        int t = tid >> 3, ww = tid & 7;
        dsh[ww][t] = delta[(size_t)(r0 + t) * DI + dg * 8 + ww];
        xsh[ww][t] = xcv[(size_t)(r0 + t) * DI + dg * 8 + ww];
        zsh[ww][t] = xz[(size_t)(r0 + t) * (2 * DI) + DI + dg * 8 + ww];
    }
    __syncthreads();

    float a  = -__expf(A_log[d * DS + lane]);
    float Dv = Dp[d];
    float vd  = dsh[w][lane];
    float vpx = vd * xsh[w][lane];
    float h = hstart[((size_t)bc * DI + d) * 64 + lane];
    float* Pw = P[w];
    float yreg = 0.f;
    const int tr = lane & 7, q = lane >> 3;

    #pragma unroll
    for (int t8 = 0; t8 < 8; ++t8) {
        #pragma unroll
        for (int tt = 0; tt < 8; ++tt) {
            int t = t8 * 8 + tt;
            unsigned int bcp = BCsh[t][lane];
            float Bt = __uint_as_float(bcp << 16);
            float Ct = __uint_as_float(bcp & 0xFFFF0000u);
            float dt_ = rdl(vd, t);
            float px  = rdl(vpx, t);
            h = h * __expf(dt_ * a) + px * Bt;
            Pw[tt * 65 + lane] = h * Ct;
        }
        // reduce: lane (q = s-octet, tr = t-in-batch); 8 partials then 3 shuffles
        float sacc = 0.f;
        #pragma unroll
        for (int j = 0; j < 8; ++j) sacc += Pw[tr * 65 + q * 8 + j];
        sacc += __shfl_xor(sacc, 8);
        sacc += __shfl_xor(sacc, 16);
        sacc += __shfl_xor(sacc, 32);
        if (q == t8) yreg = sacc;   // lane l owns t = l  (l = t8*8 + tr)
    }

    float yv = (yreg + xsh[w][lane] * Dv) * silu_f(zsh[w][lane]);

    // block-wide transpose (reuse P as T[64][9]) -> y_row[t][d] bf16
    __syncthreads();                      // all waves done with P
    float* T = (float*)P;
    T[lane * 9 + w] = yv;                 // stride 9: 2-way max
    __syncthreads();
    {
        int t = tid >> 3, dd = tid & 7;
        float v = T[t * 9 + dd];
        y_row[(size_t)(r0 + t) * DI + dg * 8 + dd] = __float2bfloat16(v);
    }
}

extern "C" void kernel_launch(void* const* d_in, const int* in_sizes, int n_in,
                              void* d_out, int out_size, void* d_ws, size_t ws_size,
                              hipStream_t stream) {
    const float* frames = (const float*)d_in[0];
    const float* gamma  = (const float*)d_in[1];
    const float* beta   = (const float*)d_in[2];
    const float* W_in   = (const float*)d_in[3];
    const float* conv_w = (const float*)d_in[4];
    const float* conv_b = (const float*)d_in[5];
    const float* W_x    = (const float*)d_in[6];
    const float* W_dt   = (const float*)d_in[7];
    const float* b_dt   = (const float*)d_in[8];
    const float* A_log  = (const float*)d_in[9];
    const float* Dp     = (const float*)d_in[10];
    const float* W_out  = (const float*)d_in[11];
    float* out = (float*)d_out;

    // workspace carve-up (bytes)
    char* ws = (char*)d_ws;
    __hip_bfloat16* xn_bf  = (__hip_bfloat16*)ws; ws += (size_t)NROWS * DM * 2;
    __hip_bfloat16* Wt_in  = (__hip_bfloat16*)ws; ws += (size_t)(2 * DI) * DM * 2;
    __hip_bfloat16* Wt_out = (__hip_bfloat16*)ws; ws += (size_t)DM * DI * 2;
    __hip_bfloat16* Wt_x   = (__hip_bfloat16*)ws; ws += (size_t)XDBW * DI * 2;
    __hip_bfloat16* y_row  = (__hip_bfloat16*)ws; ws += (size_t)NROWS * DI * 2;
    __hip_bfloat16* xcv_bf = (__hip_bfloat16*)ws; ws += (size_t)NROWS * DI * 2;
    float* xz     = (float*)ws;  ws += (size_t)NROWS * 2 * DI * 4;
    float* xcv    = (float*)ws;  ws += (size_t)NROWS * DI * 4;
    float* xdb    = (float*)ws;  ws += (size_t)NROWS * XDBW * 4;
    float* delta  = (float*)ws;  ws += (size_t)NROWS * DI * 4;
    float* hend   = (float*)ws;  ws += (size_t)Bn * NC * DI * 64 * 4;
    float* hstart = (float*)ws;  ws += (size_t)Bn * NC * DI * 64 * 4;
    float* dsum   = (float*)ws;  ws += (size_t)Bn * NC * DI * 4;

    // fused weight cast+transpose (W_in, W_out, W_x)
    transpose_cast3<<<432, 256, 0, stream>>>(W_in, W_out, W_x, Wt_in, Wt_out, Wt_x);

    ln_kernel<<<NROWS, 256, 0, stream>>>(frames, gamma, beta, xn_bf);

    // in_proj: xz = xn @ W_in  (M=2048, N=2048, K=512), 128-tile (256 blocks)
    gemm_bf16<false><<<dim3(2 * DI / 128, NROWS / 128), 256, 0, stream>>>(
        xn_bf, Wt_in, nullptr, xz, NROWS, 2 * DI, DM);

    conv_silu<<<(NROWS * DI) / 256, 256, 0, stream>>>(xz, conv_w, conv_b, xcv, xcv_bf);

    // xdb = xcv @ W_x  (M=2048, N=160, K=1024), 64-tile (96 blocks)
    gemm_bf16_64<false><<<dim3((XDBW + 63) / 64, NROWS / 64), 256, 0, stream>>>(
        xcv_bf, Wt_x, nullptr, xdb, NROWS, XDBW, DI);

    delta_kernel<<<dim3(DI / 256, NROWS), 256, 0, stream>>>(xdb, W_dt, b_dt, delta);

    // chunked selective scan
    scan_chunk1<<<Bn * NC * (DI / 8), 512, 0, stream>>>(delta, xcv, xdb, A_log, hend, dsum);
    scan_stitch<<<Bn * DI / 4, 256, 0, stream>>>(hend, dsum, A_log, hstart);
    scan_chunk2<<<Bn * NC * (DI / 8), 512, 0, stream>>>(delta, xcv, xdb, xz, A_log, Dp, hstart, y_row);

    // out_proj: out = y_row @ W_out + frames  (M=2048, N=512, K=1024), 64-tile (256 blocks)
    gemm_bf16_64<true><<<dim3(DM / 64, NROWS / 64), 256, 0, stream>>>(
        y_row, Wt_out, frames, out, NROWS, DM, DI);
}

// Round 10
// 239.170 us; speedup vs baseline: 1.2436x; 1.0324x over previous
//
#include <hip/hip_runtime.h>
#include <hip/hip_bf16.h>
#include <math.h>

// Problem constants
constexpr int Bn     = 2;
constexpr int Lseq   = 1024;
constexpr int DM     = 512;    // d_model
constexpr int DI     = 1024;   // d_inner
constexpr int DS     = 64;     // d_state
constexpr int RNK    = 32;     // dt_rank
constexpr int NROWS  = Bn * Lseq;  // 2048
constexpr int XDBW   = RNK + 2 * DS; // 160
constexpr int CH     = 64;     // scan chunk length
constexpr int NC     = Lseq / CH;  // 16 chunks

typedef __attribute__((ext_vector_type(4))) float floatx4;
typedef __attribute__((ext_vector_type(8))) short shortx8;

__device__ __forceinline__ float silu_f(float v) {
    return v / (1.f + __expf(-v));
}

__device__ __forceinline__ float rdl(float v, int l) {
    return __int_as_float(__builtin_amdgcn_readlane(__float_as_int(v), l));
}

// ---------------- LayerNorm -> bf16 ----------------
__global__ void ln_kernel(const float* __restrict__ x, const float* __restrict__ g,
                          const float* __restrict__ be, __hip_bfloat16* __restrict__ xn) {
    int row = blockIdx.x;
    int tid = threadIdx.x;
    const float* xr = x + (size_t)row * DM;
    float v0 = xr[tid], v1 = xr[tid + 256];
    float s = v0 + v1, sq = v0 * v0 + v1 * v1;
    #pragma unroll
    for (int o = 1; o < 64; o <<= 1) {
        s  += __shfl_xor(s, o);
        sq += __shfl_xor(sq, o);
    }
    __shared__ float red[8];
    int w = tid >> 6;
    if ((tid & 63) == 0) { red[w] = s; red[4 + w] = sq; }
    __syncthreads();
    float ts = red[0] + red[1] + red[2] + red[3];
    float tq = red[4] + red[5] + red[6] + red[7];
    float mu  = ts * (1.f / DM);
    float var = tq * (1.f / DM) - mu * mu;
    float inv = rsqrtf(var + 1e-5f);
    __hip_bfloat16* o0 = xn + (size_t)row * DM;
    o0[tid]       = __float2bfloat16((v0 - mu) * inv * g[tid]       + be[tid]);
    o0[tid + 256] = __float2bfloat16((v1 - mu) * inv * g[tid + 256] + be[tid + 256]);
}

// ---------------- Fused 3-way weight transpose+cast (one launch) ----------------
__global__ void transpose_cast3(const float* __restrict__ Wi, const float* __restrict__ Wo,
                                const float* __restrict__ Wx,
                                __hip_bfloat16* __restrict__ Ti, __hip_bfloat16* __restrict__ To,
                                __hip_bfloat16* __restrict__ Tx) {
    __shared__ float tile[64][65];
    int bid = blockIdx.x;
    const float* in; __hip_bfloat16* out; int R, Cc, bx, by;
    if (bid < 256)      { in = Wi; out = Ti; R = DM; Cc = 2 * DI; bx = bid & 31;        by = bid >> 5; }
    else if (bid < 384) { int b2 = bid - 256; in = Wo; out = To; R = DI; Cc = DM;   bx = b2 & 7;  by = b2 >> 3; }
    else                { int b2 = bid - 384; in = Wx; out = Tx; R = DI; Cc = XDBW; bx = b2 % 3;  by = b2 / 3; }
    int r0 = by * 64, c0 = bx * 64;
    int tid = threadIdx.x;
    #pragma unroll
    for (int i = tid; i < 4096; i += 256) {
        int r = i >> 6, c = i & 63;
        tile[r][c] = (r0 + r < R && c0 + c < Cc) ? in[(size_t)(r0 + r) * Cc + c0 + c] : 0.f;
    }
    __syncthreads();
    #pragma unroll
    for (int i = tid; i < 4096; i += 256) {
        int c = i >> 6, r = i & 63;
        if (r0 + r < R && c0 + c < Cc)
            out[(size_t)(c0 + c) * R + r0 + r] = __float2bfloat16(tile[r][c]);
    }
}

// ---------------- bf16 MFMA GEMM 128x128 tile, 512 threads (8 waves, 2x4) ----------------
// Wave-tile 64x32: a-frags 4, b-frags 2, 8 MFMA per K-iter; 2 waves/SIMD.
template<bool RES>
__global__ __launch_bounds__(512) void gemm_bf16_512(const __hip_bfloat16* __restrict__ A,
                                                     const __hip_bfloat16* __restrict__ Bt,
                                                     const float* __restrict__ Res,
                                                     float* __restrict__ C,
                                                     int M, int N, int K) {
    __shared__ __hip_bfloat16 As[128 * 32];
    __shared__ __hip_bfloat16 Bs[128 * 32];
    const int tid  = threadIdx.x;
    const int wave = tid >> 6, lane = tid & 63;
    const int m0 = blockIdx.y * 128, n0 = blockIdx.x * 128;
    const int wm = (wave >> 2) * 64, wn = (wave & 3) * 32;

    floatx4 acc[4][2] = {};

    const int arow16 = lane & 15;
    const int kgrp   = lane >> 4;

    for (int k0 = 0; k0 < K; k0 += 32) {
        {
            int i   = tid;                 // 0..511
            int row = i >> 2, seg = i & 3;
            int brow = n0 + row; if (brow >= N) brow = N - 1;
            const __hip_bfloat16* gA = A  + (size_t)(m0 + row) * K + k0 + seg * 8;
            const __hip_bfloat16* gB = Bt + (size_t)brow * K + k0 + seg * 8;
            __hip_bfloat16* lA = As + (size_t)(wave * 64) * 8;   // wave-uniform base + lane*16B
            __hip_bfloat16* lB = Bs + (size_t)(wave * 64) * 8;
            __builtin_amdgcn_global_load_lds(
                (const __attribute__((address_space(1))) void*)gA,
                (__attribute__((address_space(3))) void*)lA, 16, 0, 0);
            __builtin_amdgcn_global_load_lds(
                (const __attribute__((address_space(1))) void*)gB,
                (__attribute__((address_space(3))) void*)lB, 16, 0, 0);
        }
        __syncthreads();

        const shortx8* Asv = (const shortx8*)As;
        const shortx8* Bsv = (const shortx8*)Bs;
        shortx8 a[4], b[2];
        #pragma unroll
        for (int i = 0; i < 4; ++i)
            a[i] = Asv[(wm + i * 16 + arow16) * 4 + kgrp];
        #pragma unroll
        for (int j = 0; j < 2; ++j)
            b[j] = Bsv[(wn + j * 16 + arow16) * 4 + kgrp];
        #pragma unroll
        for (int i = 0; i < 4; ++i)
            #pragma unroll
            for (int j = 0; j < 2; ++j)
                acc[i][j] = __builtin_amdgcn_mfma_f32_16x16x32_bf16(a[i], b[j], acc[i][j], 0, 0, 0);
        __syncthreads();
    }

    const int drow = (lane >> 4) * 4;
    const int dcol = lane & 15;
    #pragma unroll
    for (int i = 0; i < 4; ++i)
        #pragma unroll
        for (int j = 0; j < 2; ++j) {
            int rowb = m0 + wm + i * 16 + drow;
            int col  = n0 + wn + j * 16 + dcol;
            if (col < N) {
                #pragma unroll
                for (int r = 0; r < 4; ++r) {
                    size_t idx = (size_t)(rowb + r) * N + col;
                    float v = acc[i][j][r];
                    if (RES) v += Res[idx];
                    C[idx] = v;
                }
            }
        }
}

// ---------------- bf16 MFMA GEMM 64x64 tile, 512 thr, in-block split-K ----------------
// Waves 0-3 accumulate K[0:K/2), waves 4-7 K[K/2:K); private LDS tiles per group;
// one cross-group LDS reduce (stride-17 pad, <=2-way) in the epilogue. 2 waves/SIMD.
template<bool RES>
__global__ __launch_bounds__(512) void gemm64_sk(const __hip_bfloat16* __restrict__ A,
                                                 const __hip_bfloat16* __restrict__ Bt,
                                                 const float* __restrict__ Res,
                                                 float* __restrict__ C,
                                                 int M, int N, int K) {
    __shared__ __hip_bfloat16 As[2][64 * 32];
    __shared__ __hip_bfloat16 Bs[2][64 * 32];
    __shared__ float red[256 * 17];    // group-1 acc dump, stride 17 (2-way max)
    const int tid  = threadIdx.x;
    const int wave = tid >> 6, lane = tid & 63;
    const int g = wave >> 2, w2 = wave & 3;
    const int m0 = blockIdx.y * 64, n0 = blockIdx.x * 64;
    const int wm = (w2 >> 1) * 32, wn = (w2 & 1) * 32;

    floatx4 acc[2][2] = {};

    const int arow16 = lane & 15;
    const int kgrp   = lane >> 4;
    const int kbeg   = g * (K / 2);

    for (int kk = 0; kk < K / 2; kk += 32) {
        int k0 = kbeg + kk;
        {
            int i   = w2 * 64 + lane;     // 0..255 within group
            int row = i >> 2, seg = i & 3;
            int brow = n0 + row; if (brow >= N) brow = N - 1;
            const __hip_bfloat16* gA = A  + (size_t)(m0 + row) * K + k0 + seg * 8;
            const __hip_bfloat16* gB = Bt + (size_t)brow * K + k0 + seg * 8;
            __hip_bfloat16* lA = As[g] + (size_t)(w2 * 64) * 8;
            __hip_bfloat16* lB = Bs[g] + (size_t)(w2 * 64) * 8;
            __builtin_amdgcn_global_load_lds(
                (const __attribute__((address_space(1))) void*)gA,
                (__attribute__((address_space(3))) void*)lA, 16, 0, 0);
            __builtin_amdgcn_global_load_lds(
                (const __attribute__((address_space(1))) void*)gB,
                (__attribute__((address_space(3))) void*)lB, 16, 0, 0);
        }
        __syncthreads();

        const shortx8* Asv = (const shortx8*)As[g];
        const shortx8* Bsv = (const shortx8*)Bs[g];
        shortx8 a[2], b[2];
        #pragma unroll
        for (int i = 0; i < 2; ++i)
            a[i] = Asv[(wm + i * 16 + arow16) * 4 + kgrp];
        #pragma unroll
        for (int j = 0; j < 2; ++j)
            b[j] = Bsv[(wn + j * 16 + arow16) * 4 + kgrp];
        #pragma unroll
        for (int i = 0; i < 2; ++i)
            #pragma unroll
            for (int j = 0; j < 2; ++j)
                acc[i][j] = __builtin_amdgcn_mfma_f32_16x16x32_bf16(a[i], b[j], acc[i][j], 0, 0, 0);
        __syncthreads();
    }

    // cross-group reduce: group 1 dumps, group 0 adds + stores
    int rbase = (w2 * 64 + lane) * 17;
    if (g == 1) {
        #pragma unroll
        for (int i = 0; i < 2; ++i)
            #pragma unroll
            for (int j = 0; j < 2; ++j)
                *(float4*)&red[rbase + (i * 2 + j) * 4] =
                    make_float4(acc[i][j][0], acc[i][j][1], acc[i][j][2], acc[i][j][3]);
    }
    __syncthreads();
    if (g == 0) {
        const int drow = (lane >> 4) * 4;
        const int dcol = lane & 15;
        #pragma unroll
        for (int i = 0; i < 2; ++i)
            #pragma unroll
            for (int j = 0; j < 2; ++j) {
                float4 part = *(const float4*)&red[rbase + (i * 2 + j) * 4];
                int rowb = m0 + wm + i * 16 + drow;
                int col  = n0 + wn + j * 16 + dcol;
                if (col < N) {
                    #pragma unroll
                    for (int r = 0; r < 4; ++r) {
                        size_t idx = (size_t)(rowb + r) * N + col;
                        float v = acc[i][j][r] + (&part.x)[r];
                        if (RES) v += Res[idx];
                        C[idx] = v;
                    }
                }
            }
    }
}

// ---------------- Causal depthwise conv (taps=4) + bias + SiLU, dual fp32/bf16 out -------
__global__ void conv_silu(const float* __restrict__ xz, const float* __restrict__ cw,
                          const float* __restrict__ cb, float* __restrict__ xcv,
                          __hip_bfloat16* __restrict__ xcv_bf) {
    int idx = blockIdx.x * 256 + threadIdx.x;   // (b*L + t)*DI + d
    int d = idx & (DI - 1);
    int bt = idx / DI;
    int t = bt & (Lseq - 1);
    int b = bt / Lseq;
    float acc = cb[d];
    #pragma unroll
    for (int k = 0; k < 4; ++k) {
        int tt = t - 3 + k;
        float xv = (tt >= 0) ? xz[((size_t)(b * Lseq + tt)) * (2 * DI) + d] : 0.f;
        acc += xv * cw[d * 4 + k];
    }
    float v = silu_f(acc);
    xcv[idx] = v;
    xcv_bf[idx] = __float2bfloat16(v);
}

// ---------------- delta = softplus(dt @ W_dt + b_dt) ----------------
__global__ void delta_kernel(const float* __restrict__ xdb, const float* __restrict__ Wdt,
                             const float* __restrict__ bdt, float* __restrict__ delta) {
    int row = blockIdx.y;
    int d = blockIdx.x * 256 + threadIdx.x;
    __shared__ float dtv[RNK];
    if (threadIdx.x < RNK) dtv[threadIdx.x] = xdb[(size_t)row * XDBW + threadIdx.x];
    __syncthreads();
    float acc = bdt[d];
    #pragma unroll
    for (int r = 0; r < RNK; ++r) acc += dtv[r] * Wdt[(size_t)r * DI + d];
    float sp = (acc > 20.f) ? acc : log1pf(__expf(acc));
    delta[(size_t)row * DI + d] = sp;
}

// ============ Chunked scan, phase 1: local scan per chunk (h0=0) + chunk delta-sum =======
__global__ __launch_bounds__(512) void scan_chunk1(
        const float* __restrict__ delta, const float* __restrict__ xcv,
        const float* __restrict__ xdb, const float* __restrict__ A_log,
        float* __restrict__ hend, float* __restrict__ dsum) {
    __shared__ float Bsh[64][68];
    __shared__ float dsh[8][64];
    __shared__ float xsh[8][64];

    int blk = blockIdx.x;
    int dg  = blk & (DI / 8 - 1);   // 0..127
    int bc  = blk >> 7;             // b*NC + c
    int c = bc & (NC - 1), b = bc >> 4;
    int tid = threadIdx.x, w = tid >> 6, lane = tid & 63;
    int d = dg * 8 + w;
    int r0 = b * Lseq + c * CH;

    // stage B (cols 32..95 of xdb), float4
    #pragma unroll
    for (int k = 0; k < 2; ++k) {
        int idx = tid + k * 512;          // 0..1023
        int row = idx >> 4, j4 = idx & 15;
        float4 v = *(const float4*)&xdb[(size_t)(r0 + row) * XDBW + RNK + j4 * 4];
        *(float4*)&Bsh[row][j4 * 4] = v;
    }
    {
        int t = tid >> 3, ww = tid & 7;
        dsh[ww][t] = delta[(size_t)(r0 + t) * DI + dg * 8 + ww];
        xsh[ww][t] = xcv[(size_t)(r0 + t) * DI + dg * 8 + ww];
    }
    __syncthreads();

    float a = -__expf(A_log[d * DS + lane]);
    float vd  = dsh[w][lane];           // delta for t=lane
    float vpx = vd * xsh[w][lane];      // delta*x for t=lane
    float h = 0.f;
    #pragma unroll 16
    for (int t = 0; t < CH; ++t) {
        float dt_ = rdl(vd, t);
        float px  = rdl(vpx, t);
        h = h * __expf(dt_ * a) + px * Bsh[t][lane];
    }
    float S = vd;
    #pragma unroll
    for (int o = 1; o < 64; o <<= 1) S += __shfl_xor(S, o);
    size_t base = ((size_t)bc * DI + d) * 64;
    hend[base + lane] = h;
    if (lane == 0) dsum[(size_t)bc * DI + d] = S;
}

// ============ Chunked scan, phase 2: stitch across chunks ============
__global__ __launch_bounds__(256) void scan_stitch(
        const float* __restrict__ hend, const float* __restrict__ dsum,
        const float* __restrict__ A_log, float* __restrict__ hstart) {
    int idx = blockIdx.x * 4 + (threadIdx.x >> 6);   // b*DI + d
    int lane = threadIdx.x & 63;
    int b = idx >> 10, d = idx & (DI - 1);
    float a = -__expf(A_log[d * DS + lane]);
    float h = 0.f;
    #pragma unroll
    for (int c = 0; c < NC; ++c) {
        size_t base = ((size_t)(b * NC + c) * DI + d) * 64;
        hstart[base + lane] = h;
        float he = hend[base + lane];
        float S  = dsum[(size_t)(b * NC + c) * DI + d];
        h = he + __expf(a * S) * h;
    }
}

// ============ Chunked scan, phase 3: recompute with h_start, emit gated y_row bf16 ======
__global__ __launch_bounds__(512) void scan_chunk2(
        const float* __restrict__ delta, const float* __restrict__ xcv,
        const float* __restrict__ xdb, const float* __restrict__ xz,
        const float* __restrict__ A_log, const float* __restrict__ Dp,
        const float* __restrict__ hstart, __hip_bfloat16* __restrict__ y_row) {
    __shared__ unsigned int BCsh[64][65];  // [t][s] = (C & 0xFFFF0000) | (B >> 16)
    __shared__ float dsh[8][64];
    __shared__ float xsh[8][64];
    __shared__ float zsh[8][64];
    __shared__ float P[8][8 * 65];

    int blk = blockIdx.x;
    int dg  = blk & (DI / 8 - 1);
    int bc  = blk >> 7;
    int c = bc & (NC - 1), b = bc >> 4;
    int tid = threadIdx.x, w = tid >> 6, lane = tid & 63;
    int d = dg * 8 + w;
    int r0 = b * Lseq + c * CH;

    // stage BC packed: thread handles (t, s-group of 4); b128 write, 2-way max
    #pragma unroll
    for (int k = 0; k < 2; ++k) {
        int i = tid + k * 512;            // 0..1023
        int t = i >> 4, sg = i & 15;
        const float* rowp = &xdb[(size_t)(r0 + t) * XDBW + RNK];
        float4 bv = *(const float4*)&rowp[sg * 4];
        float4 cv = *(const float4*)&rowp[DS + sg * 4];
        uint4 pk;
        #pragma unroll
        for (int j = 0; j < 4; ++j) {
            unsigned int bb = __float_as_uint((&bv.x)[j]);
            unsigned int cc2 = __float_as_uint((&cv.x)[j]);
            (&pk.x)[j] = (cc2 & 0xFFFF0000u) | (bb >> 16);
        }
        *(uint4*)&BCsh[t][sg * 4] = pk;
    }
    {
        int t = tid >> 3, ww = tid & 7;
        dsh[ww][t] = delta[(size_t)(r0 + t) * DI + dg * 8 + ww];
        xsh[ww][t] = xcv[(size_t)(r0 + t) * DI + dg * 8 + ww];
        zsh[ww][t] = xz[(size_t)(r0 + t) * (2 * DI) + DI + dg * 8 + ww];
    }
    __syncthreads();

    float a  = -__expf(A_log[d * DS + lane]);
    float Dv = Dp[d];
    float vd  = dsh[w][lane];
    float vpx = vd * xsh[w][lane];
    float h = hstart[((size_t)bc * DI + d) * 64 + lane];
    float* Pw = P[w];
    float yreg = 0.f;
    const int tr = lane & 7, q = lane >> 3;

    #pragma unroll
    for (int t8 = 0; t8 < 8; ++t8) {
        #pragma unroll
        for (int tt = 0; tt < 8; ++tt) {
            int t = t8 * 8 + tt;
            unsigned int bcp = BCsh[t][lane];
            float Bt = __uint_as_float(bcp << 16);
            float Ct = __uint_as_float(bcp & 0xFFFF0000u);
            float dt_ = rdl(vd, t);
            float px  = rdl(vpx, t);
            h = h * __expf(dt_ * a) + px * Bt;
            Pw[tt * 65 + lane] = h * Ct;
        }
        // reduce: lane (q = s-octet, tr = t-in-batch); 8 partials then 3 shuffles
        float sacc = 0.f;
        #pragma unroll
        for (int j = 0; j < 8; ++j) sacc += Pw[tr * 65 + q * 8 + j];
        sacc += __shfl_xor(sacc, 8);
        sacc += __shfl_xor(sacc, 16);
        sacc += __shfl_xor(sacc, 32);
        if (q == t8) yreg = sacc;   // lane l owns t = l  (l = t8*8 + tr)
    }

    float yv = (yreg + xsh[w][lane] * Dv) * silu_f(zsh[w][lane]);

    // block-wide transpose (reuse P as T[64][9]) -> y_row[t][d] bf16
    __syncthreads();                      // all waves done with P
    float* T = (float*)P;
    T[lane * 9 + w] = yv;                 // stride 9: 2-way max
    __syncthreads();
    {
        int t = tid >> 3, dd = tid & 7;
        float v = T[t * 9 + dd];
        y_row[(size_t)(r0 + t) * DI + dg * 8 + dd] = __float2bfloat16(v);
    }
}

extern "C" void kernel_launch(void* const* d_in, const int* in_sizes, int n_in,
                              void* d_out, int out_size, void* d_ws, size_t ws_size,
                              hipStream_t stream) {
    const float* frames = (const float*)d_in[0];
    const float* gamma  = (const float*)d_in[1];
    const float* beta   = (const float*)d_in[2];
    const float* W_in   = (const float*)d_in[3];
    const float* conv_w = (const float*)d_in[4];
    const float* conv_b = (const float*)d_in[5];
    const float* W_x    = (const float*)d_in[6];
    const float* W_dt   = (const float*)d_in[7];
    const float* b_dt   = (const float*)d_in[8];
    const float* A_log  = (const float*)d_in[9];
    const float* Dp     = (const float*)d_in[10];
    const float* W_out  = (const float*)d_in[11];
    float* out = (float*)d_out;

    // workspace carve-up (bytes)
    char* ws = (char*)d_ws;
    __hip_bfloat16* xn_bf  = (__hip_bfloat16*)ws; ws += (size_t)NROWS * DM * 2;
    __hip_bfloat16* Wt_in  = (__hip_bfloat16*)ws; ws += (size_t)(2 * DI) * DM * 2;
    __hip_bfloat16* Wt_out = (__hip_bfloat16*)ws; ws += (size_t)DM * DI * 2;
    __hip_bfloat16* Wt_x   = (__hip_bfloat16*)ws; ws += (size_t)XDBW * DI * 2;
    __hip_bfloat16* y_row  = (__hip_bfloat16*)ws; ws += (size_t)NROWS * DI * 2;
    __hip_bfloat16* xcv_bf = (__hip_bfloat16*)ws; ws += (size_t)NROWS * DI * 2;
    float* xz     = (float*)ws;  ws += (size_t)NROWS * 2 * DI * 4;
    float* xcv    = (float*)ws;  ws += (size_t)NROWS * DI * 4;
    float* xdb    = (float*)ws;  ws += (size_t)NROWS * XDBW * 4;
    float* delta  = (float*)ws;  ws += (size_t)NROWS * DI * 4;
    float* hend   = (float*)ws;  ws += (size_t)Bn * NC * DI * 64 * 4;
    float* hstart = (float*)ws;  ws += (size_t)Bn * NC * DI * 64 * 4;
    float* dsum   = (float*)ws;  ws += (size_t)Bn * NC * DI * 4;

    // fused weight cast+transpose (W_in, W_out, W_x)
    transpose_cast3<<<432, 256, 0, stream>>>(W_in, W_out, W_x, Wt_in, Wt_out, Wt_x);

    ln_kernel<<<NROWS, 256, 0, stream>>>(frames, gamma, beta, xn_bf);

    // in_proj: xz = xn @ W_in  (M=2048, N=2048, K=512), 128-tile 512-thr (256 blocks, 2 w/SIMD)
    gemm_bf16_512<false><<<dim3(2 * DI / 128, NROWS / 128), 512, 0, stream>>>(
        xn_bf, Wt_in, nullptr, xz, NROWS, 2 * DI, DM);

    conv_silu<<<(NROWS * DI) / 256, 256, 0, stream>>>(xz, conv_w, conv_b, xcv, xcv_bf);

    // xdb = xcv @ W_x  (M=2048, N=160, K=1024), 64-tile split-K (96 blocks, 8 waves)
    gemm64_sk<false><<<dim3((XDBW + 63) / 64, NROWS / 64), 512, 0, stream>>>(
        xcv_bf, Wt_x, nullptr, xdb, NROWS, XDBW, DI);

    delta_kernel<<<dim3(DI / 256, NROWS), 256, 0, stream>>>(xdb, W_dt, b_dt, delta);

    // chunked selective scan
    scan_chunk1<<<Bn * NC * (DI / 8), 512, 0, stream>>>(delta, xcv, xdb, A_log, hend, dsum);
    scan_stitch<<<Bn * DI / 4, 256, 0, stream>>>(hend, dsum, A_log, hstart);
    scan_chunk2<<<Bn * NC * (DI / 8), 512, 0, stream>>>(delta, xcv, xdb, xz, A_log, Dp, hstart, y_row);

    // out_proj: out = y_row @ W_out + frames  (M=2048, N=512, K=1024), 64-tile split-K (256 blocks)
    gemm64_sk<true><<<dim3(DM / 64, NROWS / 64), 512, 0, stream>>>(
        y_row, Wt_out, frames, out, NROWS, DM, DI);
}

// Round 11
// 236.321 us; speedup vs baseline: 1.2586x; 1.0121x over previous
//
#include <hip/hip_runtime.h>
#include <hip/hip_bf16.h>
#include <math.h>

// Problem constants
constexpr int Bn     = 2;
constexpr int Lseq   = 1024;
constexpr int DM     = 512;    // d_model
constexpr int DI     = 1024;   // d_inner
constexpr int DS     = 64;     // d_state
constexpr int RNK    = 32;     // dt_rank
constexpr int NROWS  = Bn * Lseq;  // 2048
constexpr int XDBW   = RNK + 2 * DS; // 160
constexpr int CH     = 64;     // scan chunk length
constexpr int NC     = Lseq / CH;  // 16 chunks

typedef __attribute__((ext_vector_type(4))) float floatx4;
typedef __attribute__((ext_vector_type(8))) short shortx8;

__device__ __forceinline__ float silu_f(float v) {
    return v / (1.f + __expf(-v));
}

__device__ __forceinline__ float rdl(float v, int l) {
    return __int_as_float(__builtin_amdgcn_readlane(__float_as_int(v), l));
}

__device__ __forceinline__ float bf2f(unsigned short u) {
    return __uint_as_float((unsigned)u << 16);
}

// ---------------- LayerNorm -> bf16 ----------------
__global__ void ln_kernel(const float* __restrict__ x, const float* __restrict__ g,
                          const float* __restrict__ be, __hip_bfloat16* __restrict__ xn) {
    int row = blockIdx.x;
    int tid = threadIdx.x;
    const float* xr = x + (size_t)row * DM;
    float v0 = xr[tid], v1 = xr[tid + 256];
    float s = v0 + v1, sq = v0 * v0 + v1 * v1;
    #pragma unroll
    for (int o = 1; o < 64; o <<= 1) {
        s  += __shfl_xor(s, o);
        sq += __shfl_xor(sq, o);
    }
    __shared__ float red[8];
    int w = tid >> 6;
    if ((tid & 63) == 0) { red[w] = s; red[4 + w] = sq; }
    __syncthreads();
    float ts = red[0] + red[1] + red[2] + red[3];
    float tq = red[4] + red[5] + red[6] + red[7];
    float mu  = ts * (1.f / DM);
    float var = tq * (1.f / DM) - mu * mu;
    float inv = rsqrtf(var + 1e-5f);
    __hip_bfloat16* o0 = xn + (size_t)row * DM;
    o0[tid]       = __float2bfloat16((v0 - mu) * inv * g[tid]       + be[tid]);
    o0[tid + 256] = __float2bfloat16((v1 - mu) * inv * g[tid + 256] + be[tid + 256]);
}

// ---------------- Fused 3-way weight transpose+cast (one launch) ----------------
__global__ void transpose_cast3(const float* __restrict__ Wi, const float* __restrict__ Wo,
                                const float* __restrict__ Wx,
                                __hip_bfloat16* __restrict__ Ti, __hip_bfloat16* __restrict__ To,
                                __hip_bfloat16* __restrict__ Tx) {
    __shared__ float tile[64][65];
    int bid = blockIdx.x;
    const float* in; __hip_bfloat16* out; int R, Cc, bx, by;
    if (bid < 256)      { in = Wi; out = Ti; R = DM; Cc = 2 * DI; bx = bid & 31;        by = bid >> 5; }
    else if (bid < 384) { int b2 = bid - 256; in = Wo; out = To; R = DI; Cc = DM;   bx = b2 & 7;  by = b2 >> 3; }
    else                { int b2 = bid - 384; in = Wx; out = Tx; R = DI; Cc = XDBW; bx = b2 % 3;  by = b2 / 3; }
    int r0 = by * 64, c0 = bx * 64;
    int tid = threadIdx.x;
    #pragma unroll
    for (int i = tid; i < 4096; i += 256) {
        int r = i >> 6, c = i & 63;
        tile[r][c] = (r0 + r < R && c0 + c < Cc) ? in[(size_t)(r0 + r) * Cc + c0 + c] : 0.f;
    }
    __syncthreads();
    #pragma unroll
    for (int i = tid; i < 4096; i += 256) {
        int c = i >> 6, r = i & 63;
        if (r0 + r < R && c0 + c < Cc)
            out[(size_t)(c0 + c) * R + r0 + r] = __float2bfloat16(tile[r][c]);
    }
}

// ---------------- in_proj GEMM 128x128 tile, 512 thr; writes bf16 x-half / z-half ------
__global__ __launch_bounds__(512) void gemm_inproj(const __hip_bfloat16* __restrict__ A,
                                                   const __hip_bfloat16* __restrict__ Bt,
                                                   __hip_bfloat16* __restrict__ xh,
                                                   __hip_bfloat16* __restrict__ zh,
                                                   int M, int N, int K) {
    __shared__ __hip_bfloat16 As[128 * 32];
    __shared__ __hip_bfloat16 Bs[128 * 32];
    const int tid  = threadIdx.x;
    const int wave = tid >> 6, lane = tid & 63;
    const int m0 = blockIdx.y * 128, n0 = blockIdx.x * 128;
    const int wm = (wave >> 2) * 64, wn = (wave & 3) * 32;

    floatx4 acc[4][2] = {};

    const int arow16 = lane & 15;
    const int kgrp   = lane >> 4;

    for (int k0 = 0; k0 < K; k0 += 32) {
        {
            int i   = tid;                 // 0..511
            int row = i >> 2, seg = i & 3;
            const __hip_bfloat16* gA = A  + (size_t)(m0 + row) * K + k0 + seg * 8;
            const __hip_bfloat16* gB = Bt + (size_t)(n0 + row) * K + k0 + seg * 8;
            __hip_bfloat16* lA = As + (size_t)(wave * 64) * 8;
            __hip_bfloat16* lB = Bs + (size_t)(wave * 64) * 8;
            __builtin_amdgcn_global_load_lds(
                (const __attribute__((address_space(1))) void*)gA,
                (__attribute__((address_space(3))) void*)lA, 16, 0, 0);
            __builtin_amdgcn_global_load_lds(
                (const __attribute__((address_space(1))) void*)gB,
                (__attribute__((address_space(3))) void*)lB, 16, 0, 0);
        }
        __syncthreads();

        const shortx8* Asv = (const shortx8*)As;
        const shortx8* Bsv = (const shortx8*)Bs;
        shortx8 a[4], b[2];
        #pragma unroll
        for (int i = 0; i < 4; ++i)
            a[i] = Asv[(wm + i * 16 + arow16) * 4 + kgrp];
        #pragma unroll
        for (int j = 0; j < 2; ++j)
            b[j] = Bsv[(wn + j * 16 + arow16) * 4 + kgrp];
        #pragma unroll
        for (int i = 0; i < 4; ++i)
            #pragma unroll
            for (int j = 0; j < 2; ++j)
                acc[i][j] = __builtin_amdgcn_mfma_f32_16x16x32_bf16(a[i], b[j], acc[i][j], 0, 0, 0);
        __syncthreads();
    }

    const int drow = (lane >> 4) * 4;
    const int dcol = lane & 15;
    const bool isz = (n0 >= DI);
    __hip_bfloat16* dst = isz ? zh : xh;
    const int coloff = isz ? DI : 0;
    #pragma unroll
    for (int i = 0; i < 4; ++i)
        #pragma unroll
        for (int j = 0; j < 2; ++j) {
            int rowb = m0 + wm + i * 16 + drow;
            int col  = n0 + wn + j * 16 + dcol - coloff;
            #pragma unroll
            for (int r = 0; r < 4; ++r)
                dst[(size_t)(rowb + r) * DI + col] = __float2bfloat16(acc[i][j][r]);
        }
}

// ---------------- bf16 MFMA GEMM 64x64 tile, 512 thr, in-block split-K ----------------
template<bool RES>
__global__ __launch_bounds__(512) void gemm64_sk(const __hip_bfloat16* __restrict__ A,
                                                 const __hip_bfloat16* __restrict__ Bt,
                                                 const float* __restrict__ Res,
                                                 float* __restrict__ C,
                                                 int M, int N, int K) {
    __shared__ __hip_bfloat16 As[2][64 * 32];
    __shared__ __hip_bfloat16 Bs[2][64 * 32];
    __shared__ float red[256 * 17];
    const int tid  = threadIdx.x;
    const int wave = tid >> 6, lane = tid & 63;
    const int g = wave >> 2, w2 = wave & 3;
    const int m0 = blockIdx.y * 64, n0 = blockIdx.x * 64;
    const int wm = (w2 >> 1) * 32, wn = (w2 & 1) * 32;

    floatx4 acc[2][2] = {};

    const int arow16 = lane & 15;
    const int kgrp   = lane >> 4;
    const int kbeg   = g * (K / 2);

    for (int kk = 0; kk < K / 2; kk += 32) {
        int k0 = kbeg + kk;
        {
            int i   = w2 * 64 + lane;
            int row = i >> 2, seg = i & 3;
            int brow = n0 + row; if (brow >= N) brow = N - 1;
            const __hip_bfloat16* gA = A  + (size_t)(m0 + row) * K + k0 + seg * 8;
            const __hip_bfloat16* gB = Bt + (size_t)brow * K + k0 + seg * 8;
            __hip_bfloat16* lA = As[g] + (size_t)(w2 * 64) * 8;
            __hip_bfloat16* lB = Bs[g] + (size_t)(w2 * 64) * 8;
            __builtin_amdgcn_global_load_lds(
                (const __attribute__((address_space(1))) void*)gA,
                (__attribute__((address_space(3))) void*)lA, 16, 0, 0);
            __builtin_amdgcn_global_load_lds(
                (const __attribute__((address_space(1))) void*)gB,
                (__attribute__((address_space(3))) void*)lB, 16, 0, 0);
        }
        __syncthreads();

        const shortx8* Asv = (const shortx8*)As[g];
        const shortx8* Bsv = (const shortx8*)Bs[g];
        shortx8 a[2], b[2];
        #pragma unroll
        for (int i = 0; i < 2; ++i)
            a[i] = Asv[(wm + i * 16 + arow16) * 4 + kgrp];
        #pragma unroll
        for (int j = 0; j < 2; ++j)
            b[j] = Bsv[(wn + j * 16 + arow16) * 4 + kgrp];
        #pragma unroll
        for (int i = 0; i < 2; ++i)
            #pragma unroll
            for (int j = 0; j < 2; ++j)
                acc[i][j] = __builtin_amdgcn_mfma_f32_16x16x32_bf16(a[i], b[j], acc[i][j], 0, 0, 0);
        __syncthreads();
    }

    int rbase = (w2 * 64 + lane) * 17;
    if (g == 1) {
        #pragma unroll
        for (int i = 0; i < 2; ++i)
            #pragma unroll
            for (int j = 0; j < 2; ++j)
                *(float4*)&red[rbase + (i * 2 + j) * 4] =
                    make_float4(acc[i][j][0], acc[i][j][1], acc[i][j][2], acc[i][j][3]);
    }
    __syncthreads();
    if (g == 0) {
        const int drow = (lane >> 4) * 4;
        const int dcol = lane & 15;
        #pragma unroll
        for (int i = 0; i < 2; ++i)
            #pragma unroll
            for (int j = 0; j < 2; ++j) {
                float4 part = *(const float4*)&red[rbase + (i * 2 + j) * 4];
                int rowb = m0 + wm + i * 16 + drow;
                int col  = n0 + wn + j * 16 + dcol;
                if (col < N) {
                    #pragma unroll
                    for (int r = 0; r < 4; ++r) {
                        size_t idx = (size_t)(rowb + r) * N + col;
                        float v = acc[i][j][r] + (&part.x)[r];
                        if (RES) v += Res[idx];
                        C[idx] = v;
                    }
                }
            }
    }
}

// ---------------- Tiled conv + silu + transposes ----------------
// Per (t0,d0,b) 64x64 tile: conv(x)->silu -> xcv_bf [t][d] + xcvT [d][t];
// silu(z) -> zgT [d][t]. All LDS patterns conflict-free.
__global__ __launch_bounds__(256) void conv_tile(const __hip_bfloat16* __restrict__ xh,
                                                 const __hip_bfloat16* __restrict__ zh,
                                                 const float* __restrict__ cw,
                                                 const float* __restrict__ cb,
                                                 __hip_bfloat16* __restrict__ xcv_bf,
                                                 __hip_bfloat16* __restrict__ xcvT,
                                                 __hip_bfloat16* __restrict__ zgT) {
    __shared__ float xt[67][68];
    __shared__ float tb[64][65];    // conv+silu result [t][d]
    __shared__ float tb2[64][65];   // silu(z) [t][d]
    int t0 = blockIdx.x * 64, d0 = blockIdx.y * 64, b = blockIdx.z;
    int tid = threadIdx.x;
    size_t rowbase = (size_t)b * Lseq;

    // stage x rows t0-3 .. t0+63 (67 rows x 64 d, bf16 -> fp32)
    for (int i = tid; i < 67 * 16; i += 256) {
        int r = i >> 4, j = i & 15;
        int t = t0 - 3 + r;
        float4 v4 = make_float4(0.f, 0.f, 0.f, 0.f);
        if (t >= 0) {
            ushort4 u = *(const ushort4*)&xh[(rowbase + t) * DI + d0 + j * 4];
            v4 = make_float4(bf2f(u.x), bf2f(u.y), bf2f(u.z), bf2f(u.w));
        }
        *(float4*)&xt[r][j * 4] = v4;
    }
    // stage z rows t0..t0+63, silu applied
    for (int i = tid; i < 64 * 16; i += 256) {
        int r = i >> 4, j = i & 15;
        ushort4 u = *(const ushort4*)&zh[(rowbase + t0 + r) * DI + d0 + j * 4];
        tb2[r][j * 4 + 0] = silu_f(bf2f(u.x));
        tb2[r][j * 4 + 1] = silu_f(bf2f(u.y));
        tb2[r][j * 4 + 2] = silu_f(bf2f(u.z));
        tb2[r][j * 4 + 3] = silu_f(bf2f(u.w));
    }
    __syncthreads();

    // conv + silu: thread (d = lane, t = tg*16+i)
    {
        int d = tid & 63, tg = tid >> 6;
        float4 cwv = *(const float4*)&cw[(d0 + d) * 4];
        float cbv = cb[d0 + d];
        #pragma unroll
        for (int i = 0; i < 16; ++i) {
            int t = tg * 16 + i;
            float acc = cbv;
            #pragma unroll
            for (int k = 0; k < 4; ++k) acc += xt[t + k][d] * (&cwv.x)[k];
            float v = silu_f(acc);
            tb[t][d] = v;
            xcv_bf[(rowbase + t0 + t) * DI + d0 + d] = __float2bfloat16(v);
        }
    }
    __syncthreads();

    // transposed writes: thread (t2 = lane, d = dg2*16+i)
    {
        int t2 = tid & 63, dg2 = tid >> 6;
        #pragma unroll
        for (int i = 0; i < 16; ++i) {
            int d = dg2 * 16 + i;
            size_t orow = ((size_t)(b * DI + d0 + d)) * Lseq + t0 + t2;
            xcvT[orow] = __float2bfloat16(tb[t2][d]);
            zgT[orow]  = __float2bfloat16(tb2[t2][d]);
        }
    }
}

// ---------------- delta = softplus(dt @ W_dt + b_dt) ----------------
__global__ void delta_kernel(const float* __restrict__ xdb, const float* __restrict__ Wdt,
                             const float* __restrict__ bdt, float* __restrict__ delta) {
    int row = blockIdx.y;
    int d = blockIdx.x * 256 + threadIdx.x;
    __shared__ float dtv[RNK];
    if (threadIdx.x < RNK) dtv[threadIdx.x] = xdb[(size_t)row * XDBW + threadIdx.x];
    __syncthreads();
    float acc = bdt[d];
    #pragma unroll
    for (int r = 0; r < RNK; ++r) acc += dtv[r] * Wdt[(size_t)r * DI + d];
    float sp = (acc > 20.f) ? acc : log1pf(__expf(acc));
    delta[(size_t)row * DI + d] = sp;
}

// ============ Chunked scan, phase 1 ============
__global__ __launch_bounds__(512) void scan_chunk1(
        const float* __restrict__ delta, const __hip_bfloat16* __restrict__ xcvT,
        const float* __restrict__ xdb, const float* __restrict__ A_log,
        float* __restrict__ hend, float* __restrict__ dsum) {
    __shared__ float Bsh[64][68];
    __shared__ float dsh[8][64];
    __shared__ float xsh[8][64];

    int blk = blockIdx.x;
    int dg  = blk & (DI / 8 - 1);   // 0..127
    int bc  = blk >> 7;             // b*NC + c
    int c = bc & (NC - 1), b = bc >> 4;
    int tid = threadIdx.x, w = tid >> 6, lane = tid & 63;
    int d = dg * 8 + w;
    int r0 = b * Lseq + c * CH;

    // stage B (cols 32..95 of xdb), float4
    #pragma unroll
    for (int k = 0; k < 2; ++k) {
        int idx = tid + k * 512;
        int row = idx >> 4, j4 = idx & 15;
        float4 v = *(const float4*)&xdb[(size_t)(r0 + row) * XDBW + RNK + j4 * 4];
        *(float4*)&Bsh[row][j4 * 4] = v;
    }
    {
        int t = tid >> 3, ww = tid & 7;
        dsh[ww][t] = delta[(size_t)(r0 + t) * DI + dg * 8 + ww];
        // x from transposed bf16: wave w stages d-row (coalesced 128B)
        xsh[w][lane] = bf2f(((const unsigned short*)xcvT)[((size_t)(b * DI + d)) * Lseq + c * CH + lane]);
    }
    __syncthreads();

    float a = -__expf(A_log[d * DS + lane]);
    float vd  = dsh[w][lane];
    float vpx = vd * xsh[w][lane];
    float h = 0.f;
    #pragma unroll 16
    for (int t = 0; t < CH; ++t) {
        float dt_ = rdl(vd, t);
        float px  = rdl(vpx, t);
        h = h * __expf(dt_ * a) + px * Bsh[t][lane];
    }
    float S = vd;
    #pragma unroll
    for (int o = 1; o < 64; o <<= 1) S += __shfl_xor(S, o);
    size_t base = ((size_t)bc * DI + d) * 64;
    hend[base + lane] = h;
    if (lane == 0) dsum[(size_t)bc * DI + d] = S;
}

// ============ Chunked scan, phase 2: stitch across chunks ============
__global__ __launch_bounds__(256) void scan_stitch(
        const float* __restrict__ hend, const float* __restrict__ dsum,
        const float* __restrict__ A_log, float* __restrict__ hstart) {
    int idx = blockIdx.x * 4 + (threadIdx.x >> 6);   // b*DI + d
    int lane = threadIdx.x & 63;
    int b = idx >> 10, d = idx & (DI - 1);
    float a = -__expf(A_log[d * DS + lane]);
    float h = 0.f;
    #pragma unroll
    for (int c = 0; c < NC; ++c) {
        size_t base = ((size_t)(b * NC + c) * DI + d) * 64;
        hstart[base + lane] = h;
        float he = hend[base + lane];
        float S  = dsum[(size_t)(b * NC + c) * DI + d];
        h = he + __expf(a * S) * h;
    }
}

// ============ Chunked scan, phase 3: recompute with h_start, emit gated y_row bf16 ======
__global__ __launch_bounds__(512) void scan_chunk2(
        const float* __restrict__ delta, const __hip_bfloat16* __restrict__ xcvT,
        const float* __restrict__ xdb, const __hip_bfloat16* __restrict__ zgT,
        const float* __restrict__ A_log, const float* __restrict__ Dp,
        const float* __restrict__ hstart, __hip_bfloat16* __restrict__ y_row) {
    __shared__ unsigned int BCsh[64][65];  // [t][s] = (C & 0xFFFF0000) | (B >> 16)
    __shared__ float dsh[8][64];
    __shared__ float xsh[8][64];
    __shared__ float zsh[8][64];
    __shared__ float P[8][8 * 65];

    int blk = blockIdx.x;
    int dg  = blk & (DI / 8 - 1);
    int bc  = blk >> 7;
    int c = bc & (NC - 1), b = bc >> 4;
    int tid = threadIdx.x, w = tid >> 6, lane = tid & 63;
    int d = dg * 8 + w;
    int r0 = b * Lseq + c * CH;

    // stage BC packed
    #pragma unroll
    for (int k = 0; k < 2; ++k) {
        int i = tid + k * 512;
        int t = i >> 4, sg = i & 15;
        const float* rowp = &xdb[(size_t)(r0 + t) * XDBW + RNK];
        float4 bv = *(const float4*)&rowp[sg * 4];
        float4 cv = *(const float4*)&rowp[DS + sg * 4];
        uint4 pk;
        #pragma unroll
        for (int j = 0; j < 4; ++j) {
            unsigned int bb = __float_as_uint((&bv.x)[j]);
            unsigned int cc2 = __float_as_uint((&cv.x)[j]);
            (&pk.x)[j] = (cc2 & 0xFFFF0000u) | (bb >> 16);
        }
        *(uint4*)&BCsh[t][sg * 4] = pk;
    }
    {
        int t = tid >> 3, ww = tid & 7;
        dsh[ww][t] = delta[(size_t)(r0 + t) * DI + dg * 8 + ww];
        size_t trow = ((size_t)(b * DI + d)) * Lseq + c * CH + lane;
        xsh[w][lane] = bf2f(((const unsigned short*)xcvT)[trow]);
        zsh[w][lane] = bf2f(((const unsigned short*)zgT)[trow]);   // already silu'd
    }
    __syncthreads();

    float a  = -__expf(A_log[d * DS + lane]);
    float Dv = Dp[d];
    float vd  = dsh[w][lane];
    float vpx = vd * xsh[w][lane];
    float h = hstart[((size_t)bc * DI + d) * 64 + lane];
    float* Pw = P[w];
    float yreg = 0.f;
    const int tr = lane & 7, q = lane >> 3;

    #pragma unroll
    for (int t8 = 0; t8 < 8; ++t8) {
        #pragma unroll
        for (int tt = 0; tt < 8; ++tt) {
            int t = t8 * 8 + tt;
            unsigned int bcp = BCsh[t][lane];
            float Bt = __uint_as_float(bcp << 16);
            float Ct = __uint_as_float(bcp & 0xFFFF0000u);
            float dt_ = rdl(vd, t);
            float px  = rdl(vpx, t);
            h = h * __expf(dt_ * a) + px * Bt;
            Pw[tt * 65 + lane] = h * Ct;
        }
        float sacc = 0.f;
        #pragma unroll
        for (int j = 0; j < 8; ++j) sacc += Pw[tr * 65 + q * 8 + j];
        sacc += __shfl_xor(sacc, 8);
        sacc += __shfl_xor(sacc, 16);
        sacc += __shfl_xor(sacc, 32);
        if (q == t8) yreg = sacc;
    }

    float yv = (yreg + xsh[w][lane] * Dv) * zsh[w][lane];

    // block-wide transpose (reuse P as T[64][9]) -> y_row[t][d] bf16
    __syncthreads();
    float* T = (float*)P;
    T[lane * 9 + w] = yv;
    __syncthreads();
    {
        int t = tid >> 3, dd = tid & 7;
        float v = T[t * 9 + dd];
        y_row[(size_t)(r0 + t) * DI + dg * 8 + dd] = __float2bfloat16(v);
    }
}

extern "C" void kernel_launch(void* const* d_in, const int* in_sizes, int n_in,
                              void* d_out, int out_size, void* d_ws, size_t ws_size,
                              hipStream_t stream) {
    const float* frames = (const float*)d_in[0];
    const float* gamma  = (const float*)d_in[1];
    const float* beta   = (const float*)d_in[2];
    const float* W_in   = (const float*)d_in[3];
    const float* conv_w = (const float*)d_in[4];
    const float* conv_b = (const float*)d_in[5];
    const float* W_x    = (const float*)d_in[6];
    const float* W_dt   = (const float*)d_in[7];
    const float* b_dt   = (const float*)d_in[8];
    const float* A_log  = (const float*)d_in[9];
    const float* Dp     = (const float*)d_in[10];
    const float* W_out  = (const float*)d_in[11];
    float* out = (float*)d_out;

    // workspace carve-up (bytes)
    char* ws = (char*)d_ws;
    __hip_bfloat16* xn_bf  = (__hip_bfloat16*)ws; ws += (size_t)NROWS * DM * 2;
    __hip_bfloat16* Wt_in  = (__hip_bfloat16*)ws; ws += (size_t)(2 * DI) * DM * 2;
    __hip_bfloat16* Wt_out = (__hip_bfloat16*)ws; ws += (size_t)DM * DI * 2;
    __hip_bfloat16* Wt_x   = (__hip_bfloat16*)ws; ws += (size_t)XDBW * DI * 2;
    __hip_bfloat16* y_row  = (__hip_bfloat16*)ws; ws += (size_t)NROWS * DI * 2;
    __hip_bfloat16* xcv_bf = (__hip_bfloat16*)ws; ws += (size_t)NROWS * DI * 2;
    __hip_bfloat16* xh     = (__hip_bfloat16*)ws; ws += (size_t)NROWS * DI * 2;
    __hip_bfloat16* zh     = (__hip_bfloat16*)ws; ws += (size_t)NROWS * DI * 2;
    __hip_bfloat16* xcvT   = (__hip_bfloat16*)ws; ws += (size_t)NROWS * DI * 2;
    __hip_bfloat16* zgT    = (__hip_bfloat16*)ws; ws += (size_t)NROWS * DI * 2;
    float* xdb    = (float*)ws;  ws += (size_t)NROWS * XDBW * 4;
    float* delta  = (float*)ws;  ws += (size_t)NROWS * DI * 4;
    float* hend   = (float*)ws;  ws += (size_t)Bn * NC * DI * 64 * 4;
    float* hstart = (float*)ws;  ws += (size_t)Bn * NC * DI * 64 * 4;
    float* dsum   = (float*)ws;  ws += (size_t)Bn * NC * DI * 4;

    // fused weight cast+transpose (W_in, W_out, W_x)
    transpose_cast3<<<432, 256, 0, stream>>>(W_in, W_out, W_x, Wt_in, Wt_out, Wt_x);

    ln_kernel<<<NROWS, 256, 0, stream>>>(frames, gamma, beta, xn_bf);

    // in_proj -> bf16 x-half / z-half
    gemm_inproj<<<dim3(2 * DI / 128, NROWS / 128), 512, 0, stream>>>(
        xn_bf, Wt_in, xh, zh, NROWS, 2 * DI, DM);

    // conv + silu + transposes
    conv_tile<<<dim3(Lseq / 64, DI / 64, Bn), 256, 0, stream>>>(
        xh, zh, conv_w, conv_b, xcv_bf, xcvT, zgT);

    // xdb = xcv @ W_x  (M=2048, N=160, K=1024)
    gemm64_sk<false><<<dim3((XDBW + 63) / 64, NROWS / 64), 512, 0, stream>>>(
        xcv_bf, Wt_x, nullptr, xdb, NROWS, XDBW, DI);

    delta_kernel<<<dim3(DI / 256, NROWS), 256, 0, stream>>>(xdb, W_dt, b_dt, delta);

    // chunked selective scan
    scan_chunk1<<<Bn * NC * (DI / 8), 512, 0, stream>>>(delta, xcvT, xdb, A_log, hend, dsum);
    scan_stitch<<<Bn * DI / 4, 256, 0, stream>>>(hend, dsum, A_log, hstart);
    scan_chunk2<<<Bn * NC * (DI / 8), 512, 0, stream>>>(delta, xcvT, xdb, zgT, A_log, Dp, hstart, y_row);

    // out_proj: out = y_row @ W_out + frames
    gemm64_sk<true><<<dim3(DM / 64, NROWS / 64), 512, 0, stream>>>(
        y_row, Wt_out, frames, out, NROWS, DM, DI);
}